// Round 1
// baseline (384.764 us; speedup 1.0000x reference)
//
#include <hip/hip_runtime.h>
#include <math.h>

#define Bdim 4
#define Sdim 1024
#define Edim 512
#define Hdim 8
#define EPSf 1e-7f

// ws layout (floats):
//  P  (projected q,k,v): 3 * B*S*E = 3*2097152     @ 0
//  H2 (per-head norm^2): 3 * B*H*S = 3*32768       @ 6291456
//  WM (per-col meta, float4 {cosh2r/zn, sinh2r, 2zn, 0}): 3*512 float4 @ 6389760
// total ~25.6 MB

__device__ __forceinline__ float asinhf_fast(float x) {
  return logf(x + sqrtf(fmaf(x, x, 1.f)));
}

__global__ __launch_bounds__(256)
void prep_kernel(const float* __restrict__ zq, const float* __restrict__ rq,
                 const float* __restrict__ zk, const float* __restrict__ rk,
                 const float* __restrict__ zv, const float* __restrict__ rv,
                 float4* __restrict__ WM) {
  int mat = blockIdx.x >> 3;
  int cg  = blockIdx.x & 7;
  const float* z = (mat == 0) ? zq : (mat == 1) ? zk : zv;
  const float* r = (mat == 0) ? rq : (mat == 1) ? rk : rv;
  int c = threadIdx.x & 63;
  int p = threadIdx.x >> 6;
  int col = cg * 64 + c;
  float acc = 0.f;
  for (int n = p; n < Edim; n += 4) {
    float v = z[n * Edim + col];
    acc = fmaf(v, v, acc);
  }
  __shared__ float red[4][64];
  red[p][c] = acc;
  __syncthreads();
  if (threadIdx.x < 64) {
    float s  = red[0][c] + red[1][c] + red[2][c] + red[3][c];
    float zn = fmaxf(sqrtf(s), EPSf);
    float tr = 2.f * r[col];
    float e  = expf(tr), ei = 1.f / e;
    float ch = 0.5f * (e + ei), sh = 0.5f * (e - ei);
    WM[mat * Edim + col] = make_float4(ch / zn, sh, 2.f * zn, 0.f);
  }
}

__global__ __launch_bounds__(256)
void proj_kernel(const float* __restrict__ xq, const float* __restrict__ xk, const float* __restrict__ xv,
                 const float* __restrict__ zqm, const float* __restrict__ zkm, const float* __restrict__ zvm,
                 const float4* __restrict__ WM, float* __restrict__ Pbase, float* __restrict__ H2base) {
  const int mat = blockIdx.y;
  const float* X = (mat == 0) ? xq : (mat == 1) ? xk : xv;
  const float* Z = (mat == 0) ? zqm : (mat == 1) ? zkm : zvm;
  float* P  = Pbase + (size_t)mat * (Bdim * Sdim * Edim);
  float* H2 = H2base + (size_t)mat * (Bdim * Hdim * Sdim);
  const int r0 = blockIdx.x * 16;
  const int t  = threadIdx.x;
  const int wave = t >> 6;
  const int lane = t & 63;

  __shared__ __align__(16) float Xs[16 * 512];
  __shared__ float x2s[16];
  __shared__ float scs[16];
  __shared__ float wred[4][16];

  // stage 16 rows of X into LDS (coalesced float4)
  #pragma unroll
  for (int i = 0; i < 8; ++i) {
    int f  = t + 256 * i;
    int rr = f >> 7;
    int n4 = f & 127;
    float4 v = *(const float4*)(X + (size_t)(r0 + rr) * Edim + 4 * n4);
    *(float4*)(Xs + rr * 512 + 4 * n4) = v;
  }
  __syncthreads();

  // per-row |x|^2 (16 lanes per row, contiguous in wave -> shfl_xor reduce)
  {
    int rr = t >> 4, i16 = t & 15;
    float a = 0.f;
    #pragma unroll
    for (int j = 0; j < 8; ++j) {
      float4 v = *(const float4*)(Xs + rr * 512 + i16 * 32 + 4 * j);
      a = fmaf(v.x, v.x, a); a = fmaf(v.y, v.y, a);
      a = fmaf(v.z, v.z, a); a = fmaf(v.w, v.w, a);
    }
    a += __shfl_xor(a, 1); a += __shfl_xor(a, 2);
    a += __shfl_xor(a, 4); a += __shfl_xor(a, 8);
    if (i16 == 0) x2s[rr] = a;
  }
  __syncthreads();

  // GEMM: 16 rows x 512 cols; thread owns cols t and t+256 for all 16 rows
  float acc0[16], acc1[16];
  #pragma unroll
  for (int i = 0; i < 16; ++i) { acc0[i] = 0.f; acc1[i] = 0.f; }
  const int c0 = t, c1 = t + 256;

  for (int n4 = 0; n4 < 128; ++n4) {
    float z00 = Z[(n4 * 4 + 0) * Edim + c0];
    float z01 = Z[(n4 * 4 + 1) * Edim + c0];
    float z02 = Z[(n4 * 4 + 2) * Edim + c0];
    float z03 = Z[(n4 * 4 + 3) * Edim + c0];
    float z10 = Z[(n4 * 4 + 0) * Edim + c1];
    float z11 = Z[(n4 * 4 + 1) * Edim + c1];
    float z12 = Z[(n4 * 4 + 2) * Edim + c1];
    float z13 = Z[(n4 * 4 + 3) * Edim + c1];
    #pragma unroll
    for (int rr = 0; rr < 16; ++rr) {
      float4 xv4 = *(const float4*)(Xs + rr * 512 + n4 * 4);  // broadcast read
      acc0[rr] = fmaf(xv4.x, z00, acc0[rr]);
      acc0[rr] = fmaf(xv4.y, z01, acc0[rr]);
      acc0[rr] = fmaf(xv4.z, z02, acc0[rr]);
      acc0[rr] = fmaf(xv4.w, z03, acc0[rr]);
      acc1[rr] = fmaf(xv4.x, z10, acc1[rr]);
      acc1[rr] = fmaf(xv4.y, z11, acc1[rr]);
      acc1[rr] = fmaf(xv4.z, z12, acc1[rr]);
      acc1[rr] = fmaf(xv4.w, z13, acc1[rr]);
    }
  }

  // h_linear epilogue: v = 2*zn*asinh(lam*xz*ch/zn - (lam-1)*sh)
  const float4 wm0 = WM[mat * Edim + c0];
  const float4 wm1 = WM[mat * Edim + c1];
  float sq[16];
  #pragma unroll
  for (int rr = 0; rr < 16; ++rr) {
    float x2   = x2s[rr];
    float lam  = 2.f / fmaxf(1.f - x2, EPSf);
    float lam1 = lam - 1.f;
    float t0 = lam * acc0[rr] * wm0.x - lam1 * wm0.y;
    float t1 = lam * acc1[rr] * wm1.x - lam1 * wm1.y;
    float v0 = wm0.z * asinhf_fast(t0);
    float v1 = wm1.z * asinhf_fast(t1);
    acc0[rr] = v0; acc1[rr] = v1;
    sq[rr] = fmaf(v0, v0, v1 * v1);
  }
  // block-wide per-row sum of v^2
  #pragma unroll
  for (int rr = 0; rr < 16; ++rr) {
    float a = sq[rr];
    a += __shfl_xor(a, 1);  a += __shfl_xor(a, 2);  a += __shfl_xor(a, 4);
    a += __shfl_xor(a, 8);  a += __shfl_xor(a, 16); a += __shfl_xor(a, 32);
    if (lane == 0) wred[wave][rr] = a;
  }
  __syncthreads();
  if (t < 16) {
    float v2 = wred[0][t] + wred[1][t] + wred[2][t] + wred[3][t];
    scs[t] = 1.f / (1.f + sqrtf(1.f + v2));
  }
  __syncthreads();

  // scale into ball, store P, and per-head norm^2 (head = wave for c0, wave+4 for c1)
  #pragma unroll
  for (int rr = 0; rr < 16; ++rr) {
    float s  = scs[rr];
    float o0 = acc0[rr] * s, o1 = acc1[rr] * s;
    size_t row = (size_t)(r0 + rr);
    P[row * Edim + c0] = o0;
    P[row * Edim + c1] = o1;
    float a0 = o0 * o0, a1 = o1 * o1;
    a0 += __shfl_xor(a0, 1);  a0 += __shfl_xor(a0, 2);  a0 += __shfl_xor(a0, 4);
    a0 += __shfl_xor(a0, 8);  a0 += __shfl_xor(a0, 16); a0 += __shfl_xor(a0, 32);
    a1 += __shfl_xor(a1, 1);  a1 += __shfl_xor(a1, 2);  a1 += __shfl_xor(a1, 4);
    a1 += __shfl_xor(a1, 8);  a1 += __shfl_xor(a1, 16); a1 += __shfl_xor(a1, 32);
    if (lane == 0) {
      int bb = (int)(row >> 10), ss = (int)(row & 1023);
      H2[((size_t)bb * Hdim + wave) * Sdim + ss]     = a0;
      H2[((size_t)bb * Hdim + wave + 4) * Sdim + ss] = a1;
    }
  }
}

__global__ __launch_bounds__(256)
void attn_kernel(const float* __restrict__ Pbase, const float* __restrict__ H2base,
                 float* __restrict__ out) {
  const int bh = blockIdx.y;
  const int b = bh >> 3, h = bh & 7;
  const int q0 = blockIdx.x * 64;
  const int t  = threadIdx.x;
  const int tx = t & 15, ty = t >> 4;

  const float* Pq = Pbase;
  const float* Pk = Pbase + (size_t)Bdim * Sdim * Edim;
  const float* Pv = Pbase + (size_t)2 * Bdim * Sdim * Edim;
  const float* Q2 = H2base + ((size_t)b * Hdim + h) * Sdim;
  const float* K2 = H2base + (size_t)Bdim * Hdim * Sdim + ((size_t)b * Hdim + h) * Sdim;
  const float* V2 = H2base + (size_t)2 * Bdim * Hdim * Sdim + ((size_t)b * Hdim + h) * Sdim;

  __shared__ __align__(16) float QsT[64 * 68];
  __shared__ __align__(16) float KsT[64 * 68];
  __shared__ __align__(16) float Vs [64 * 68];
  __shared__ __align__(16) float WsT[64 * 68];
  __shared__ __align__(16) float k2s[64];
  __shared__ __align__(16) float cks[64];
  __shared__ __align__(16) float lamvs[64];
  __shared__ __align__(16) float lamv1s[64];

  // stage Q tile transposed: QsT[d][q]
  {
    int q = t >> 2, dg = t & 3;
    const float* src = Pq + ((size_t)(b * Sdim + q0 + q)) * Edim + h * 64 + dg * 16;
    #pragma unroll
    for (int j4 = 0; j4 < 4; ++j4) {
      float4 v = *(const float4*)(src + 4 * j4);
      int d = dg * 16 + 4 * j4;
      QsT[(d + 0) * 68 + q] = v.x;
      QsT[(d + 1) * 68 + q] = v.y;
      QsT[(d + 2) * 68 + q] = v.z;
      QsT[(d + 3) * 68 + q] = v.w;
    }
  }
  float q2r[4], aqr[4];
  #pragma unroll
  for (int i = 0; i < 4; ++i) {
    float q2 = Q2[q0 + 4 * ty + i];
    q2r[i] = q2;
    aqr[i] = 1.f / fmaxf(1.f - q2, EPSf);
  }
  float num[16], denp[4];
  #pragma unroll
  for (int i = 0; i < 16; ++i) num[i] = 0.f;
  #pragma unroll
  for (int i = 0; i < 4; ++i) denp[i] = 0.f;

  for (int kt = 0; kt < 16; ++kt) {
    __syncthreads();  // prev phase B done (and Q staging on first iter)
    {
      int k = t >> 2, dg = t & 3;
      const float* srck = Pk + ((size_t)(b * Sdim + kt * 64 + k)) * Edim + h * 64 + dg * 16;
      const float* srcv = Pv + ((size_t)(b * Sdim + kt * 64 + k)) * Edim + h * 64 + dg * 16;
      #pragma unroll
      for (int j4 = 0; j4 < 4; ++j4) {
        float4 v = *(const float4*)(srck + 4 * j4);
        int d = dg * 16 + 4 * j4;
        KsT[(d + 0) * 68 + k] = v.x;
        KsT[(d + 1) * 68 + k] = v.y;
        KsT[(d + 2) * 68 + k] = v.z;
        KsT[(d + 3) * 68 + k] = v.w;
      }
      #pragma unroll
      for (int j4 = 0; j4 < 4; ++j4) {
        float4 v = *(const float4*)(srcv + 4 * j4);
        *(float4*)(Vs + k * 68 + dg * 16 + 4 * j4) = v;
      }
    }
    if (t < 64) {
      float k2 = K2[kt * 64 + t];
      float v2 = V2[kt * 64 + t];
      k2s[t] = k2;
      cks[t] = 2.f / fmaxf(1.f - k2, EPSf);
      float lamv = 2.f / fmaxf(1.f - v2, EPSf);
      lamvs[t]  = lamv;
      lamv1s[t] = lamv - 1.f;
    }
    __syncthreads();

    // phase A: 64x64x64 QK^T micro-tiled 4x4
    float c[16];
    #pragma unroll
    for (int i = 0; i < 16; ++i) c[i] = 0.f;
    #pragma unroll 4
    for (int d = 0; d < 64; ++d) {
      float4 a4 = *(const float4*)(QsT + d * 68 + 4 * ty);
      float4 b4 = *(const float4*)(KsT + d * 68 + 4 * tx);
      c[0]  = fmaf(a4.x, b4.x, c[0]);   c[1]  = fmaf(a4.x, b4.y, c[1]);
      c[2]  = fmaf(a4.x, b4.z, c[2]);   c[3]  = fmaf(a4.x, b4.w, c[3]);
      c[4]  = fmaf(a4.y, b4.x, c[4]);   c[5]  = fmaf(a4.y, b4.y, c[5]);
      c[6]  = fmaf(a4.y, b4.z, c[6]);   c[7]  = fmaf(a4.y, b4.w, c[7]);
      c[8]  = fmaf(a4.z, b4.x, c[8]);   c[9]  = fmaf(a4.z, b4.y, c[9]);
      c[10] = fmaf(a4.z, b4.z, c[10]);  c[11] = fmaf(a4.z, b4.w, c[11]);
      c[12] = fmaf(a4.w, b4.x, c[12]);  c[13] = fmaf(a4.w, b4.y, c[13]);
      c[14] = fmaf(a4.w, b4.z, c[14]);  c[15] = fmaf(a4.w, b4.w, c[15]);
    }

    // weight chain: w = exp(-arccosh(1+u)) = (1+u) - sqrt(u*(u+2))
    float4 k2v = *(const float4*)(k2s + 4 * tx);
    float4 ckv = *(const float4*)(cks + 4 * tx);
    float4 lvv = *(const float4*)(lamvs + 4 * tx);
    float4 l1v = *(const float4*)(lamv1s + 4 * tx);
    float k2a[4] = {k2v.x, k2v.y, k2v.z, k2v.w};
    float cka[4] = {ckv.x, ckv.y, ckv.z, ckv.w};
    float lva[4] = {lvv.x, lvv.y, lvv.z, lvv.w};
    float l1a[4] = {l1v.x, l1v.y, l1v.z, l1v.w};
    float wl[16];
    #pragma unroll
    for (int i = 0; i < 4; ++i) {
      #pragma unroll
      for (int j = 0; j < 4; ++j) {
        float dot = c[i * 4 + j];
        float d2 = fmaf(-2.f, dot, q2r[i] + k2a[j]);
        d2 = fmaxf(d2, 0.f);
        float u = d2 * cka[j] * aqr[i];
        u = fmaxf(u, EPSf);
        float s = sqrtf(u * (u + 2.f));
        float w = (1.f + u) - s;
        denp[i] = fmaf(w, l1a[j], denp[i]);
        wl[i * 4 + j] = w * lva[j];  // fold lam_v into W for phase B
      }
    }
    #pragma unroll
    for (int j = 0; j < 4; ++j) {
      float4 tmp = make_float4(wl[0 * 4 + j], wl[1 * 4 + j], wl[2 * 4 + j], wl[3 * 4 + j]);
      *(float4*)(WsT + (4 * tx + j) * 68 + 4 * ty) = tmp;
    }
    __syncthreads();

    // phase B: num += W @ V
    #pragma unroll 4
    for (int kk = 0; kk < 64; ++kk) {
      float4 a4 = *(const float4*)(WsT + kk * 68 + 4 * ty);
      float4 b4 = *(const float4*)(Vs + kk * 68 + 4 * tx);
      num[0]  = fmaf(a4.x, b4.x, num[0]);   num[1]  = fmaf(a4.x, b4.y, num[1]);
      num[2]  = fmaf(a4.x, b4.z, num[2]);   num[3]  = fmaf(a4.x, b4.w, num[3]);
      num[4]  = fmaf(a4.y, b4.x, num[4]);   num[5]  = fmaf(a4.y, b4.y, num[5]);
      num[6]  = fmaf(a4.y, b4.z, num[6]);   num[7]  = fmaf(a4.y, b4.w, num[7]);
      num[8]  = fmaf(a4.z, b4.x, num[8]);   num[9]  = fmaf(a4.z, b4.y, num[9]);
      num[10] = fmaf(a4.z, b4.z, num[10]);  num[11] = fmaf(a4.z, b4.w, num[11]);
      num[12] = fmaf(a4.w, b4.x, num[12]);  num[13] = fmaf(a4.w, b4.y, num[13]);
      num[14] = fmaf(a4.w, b4.z, num[14]);  num[15] = fmaf(a4.w, b4.w, num[15]);
    }
  }

  // epilogue: midpoint + half mobius scalar-mul
  #pragma unroll
  for (int i = 0; i < 4; ++i) {
    float dsum = denp[i];
    dsum += __shfl_xor(dsum, 1); dsum += __shfl_xor(dsum, 2);
    dsum += __shfl_xor(dsum, 4); dsum += __shfl_xor(dsum, 8);
    float dv = (fabsf(dsum) < EPSf) ? EPSf : dsum;
    float inv = 1.f / dv;
    float m0 = num[i * 4 + 0] * inv, m1 = num[i * 4 + 1] * inv;
    float m2 = num[i * 4 + 2] * inv, m3 = num[i * 4 + 3] * inv;
    float p = fmaf(m0, m0, fmaf(m1, m1, fmaf(m2, m2, m3 * m3)));
    p += __shfl_xor(p, 1); p += __shfl_xor(p, 2);
    p += __shfl_xor(p, 4); p += __shfl_xor(p, 8);
    float mn  = sqrtf(p);
    float mnc = fmaxf(mn, EPSf);
    float tt  = fminf(mnc, 1.f - 1e-6f);
    // tanh(0.5*artanh(t)) = t/(1+sqrt(1-t^2))
    float scale = tt / ((1.f + sqrtf(fmaxf(1.f - tt * tt, 0.f))) * mnc);
    float4 o = make_float4(m0 * scale, m1 * scale, m2 * scale, m3 * scale);
    *(float4*)(out + ((size_t)(b * Sdim + q0 + 4 * ty + i)) * Edim + h * 64 + 4 * tx) = o;
  }
}

extern "C" void kernel_launch(void* const* d_in, const int* in_sizes, int n_in,
                              void* d_out, int out_size, void* d_ws, size_t ws_size,
                              hipStream_t stream) {
  (void)in_sizes; (void)n_in; (void)out_size; (void)ws_size;
  const float* q  = (const float*)d_in[0];
  const float* k  = (const float*)d_in[1];
  const float* v  = (const float*)d_in[2];
  const float* zq = (const float*)d_in[3];
  const float* rq = (const float*)d_in[4];
  const float* zk = (const float*)d_in[5];
  const float* rk = (const float*)d_in[6];
  const float* zv = (const float*)d_in[7];
  const float* rv = (const float*)d_in[8];
  float* ws = (float*)d_ws;
  float* P  = ws;                                   // 3 * 2097152
  float* H2 = ws + (size_t)3 * 2097152;             // 3 * 32768
  float4* WM = (float4*)(ws + (size_t)3 * 2097152 + (size_t)3 * 32768);

  hipLaunchKernelGGL(prep_kernel, dim3(24), dim3(256), 0, stream,
                     zq, rq, zk, rk, zv, rv, WM);
  hipLaunchKernelGGL(proj_kernel, dim3(256, 3), dim3(256), 0, stream,
                     q, k, v, zq, zk, zv, WM, P, H2);
  hipLaunchKernelGGL(attn_kernel, dim3(16, 32), dim3(256), 0, stream,
                     P, H2, (float*)d_out);
}

// Round 2
// 217.954 us; speedup vs baseline: 1.7653x; 1.7653x over previous
//
#include <hip/hip_runtime.h>
#include <math.h>

#define EPSf 1e-7f
typedef unsigned short u16;
typedef __attribute__((ext_vector_type(8))) short bf16x8;
typedef __attribute__((ext_vector_type(4))) float f32x4;

__device__ __forceinline__ float bf2f(u16 u) {
  union { unsigned int i; float f; } x; x.i = ((unsigned int)u) << 16; return x.f;
}
__device__ __forceinline__ u16 f2bf(float f) {  // RNE
  union { float f; unsigned int i; } x; x.f = f;
  unsigned int r = x.i + 0x7fffu + ((x.i >> 16) & 1u);
  return (u16)(r >> 16);
}
__device__ __forceinline__ void gll16(const void* g, void* l) {
  __builtin_amdgcn_global_load_lds((__attribute__((address_space(1))) void*)(g),
                                   (__attribute__((address_space(3))) void*)(l),
                                   16, 0, 0);
}

// ---------------- split_z: z -> ZhT/ZlT (transposed bf16 hi/lo) + col norms -> WM ----
// grid 24 (3 mats x 8 col-groups of 64), block 256
__global__ __launch_bounds__(256) void split_z(
    const float* __restrict__ zq, const float* __restrict__ zk, const float* __restrict__ zv,
    const float* __restrict__ rq, const float* __restrict__ rk, const float* __restrict__ rv,
    u16* __restrict__ ZhT, u16* __restrict__ ZlT, float4* __restrict__ WM) {
  const int mat = blockIdx.x >> 3;
  const int c0 = (blockIdx.x & 7) * 64;
  const float* Z = (mat == 0) ? zq : (mat == 1) ? zk : zv;
  const float* R = (mat == 0) ? rq : (mat == 1) ? rk : rv;
  __shared__ float tile[64][68];
  const int t = threadIdx.x;
  const int cl = t >> 2, kg4 = t & 3;
  const size_t zo = (size_t)mat * 512 * 512;
  float csum = 0.f;
  for (int kt = 0; kt < 8; ++kt) {
    __syncthreads();
    {
      int kl = t >> 2;
      const float* src = Z + (size_t)(kt * 64 + kl) * 512 + c0;
      #pragma unroll
      for (int j = 0; j < 4; ++j) {
        float4 v = *(const float4*)(src + (t & 3) * 16 + 4 * j);
        *(float4*)&tile[kl][(t & 3) * 16 + 4 * j] = v;
      }
    }
    __syncthreads();
    #pragma unroll
    for (int jj = 0; jj < 4; ++jj) {
      u16 hb[4], lb[4];
      #pragma unroll
      for (int qq = 0; qq < 4; ++qq) {
        float zval = tile[kg4 * 16 + jj * 4 + qq][cl];
        csum = fmaf(zval, zval, csum);
        u16 hh = f2bf(zval);
        hb[qq] = hh;
        lb[qq] = f2bf(zval - bf2f(hh));
      }
      size_t o = zo + (size_t)(c0 + cl) * 512 + kt * 64 + kg4 * 16 + jj * 4;
      *(ushort4*)(ZhT + o) = make_ushort4(hb[0], hb[1], hb[2], hb[3]);
      *(ushort4*)(ZlT + o) = make_ushort4(lb[0], lb[1], lb[2], lb[3]);
    }
  }
  csum += __shfl_xor(csum, 1);
  csum += __shfl_xor(csum, 2);
  if (kg4 == 0) {
    float zn = fmaxf(sqrtf(csum), EPSf);
    float tr = 2.f * R[c0 + cl];
    float e = expf(tr), ei = 1.f / e;
    WM[mat * 512 + c0 + cl] = make_float4(0.5f * (e + ei) / zn, 0.5f * (e - ei), 2.f * zn, 0.f);
  }
}

// ---------------- split_x: x -> Xh/Xl bf16 planes + row norms Xn + zero Vn ------------
// grid 6144 (2 rows per block over 3*4096 rows), block 256
__global__ __launch_bounds__(256) void split_x(
    const float* __restrict__ xq, const float* __restrict__ xk, const float* __restrict__ xv,
    u16* __restrict__ Xh, u16* __restrict__ Xl,
    float* __restrict__ Xn, float* __restrict__ Vn) {
  const int gr = blockIdx.x * 2 + (threadIdx.x >> 7);
  const int mat = gr >> 12, row = gr & 4095;
  const float* X = (mat == 0) ? xq : (mat == 1) ? xk : xv;
  const int f4 = threadIdx.x & 127;
  float4 x = ((const float4*)(X + (size_t)row * 512))[f4];
  u16 h0 = f2bf(x.x), h1 = f2bf(x.y), h2 = f2bf(x.z), h3 = f2bf(x.w);
  u16 l0 = f2bf(x.x - bf2f(h0)), l1 = f2bf(x.y - bf2f(h1));
  u16 l2 = f2bf(x.z - bf2f(h2)), l3 = f2bf(x.w - bf2f(h3));
  ((ushort4*)(Xh + (size_t)gr * 512))[f4] = make_ushort4(h0, h1, h2, h3);
  ((ushort4*)(Xl + (size_t)gr * 512))[f4] = make_ushort4(l0, l1, l2, l3);
  float a = fmaf(x.x, x.x, fmaf(x.y, x.y, fmaf(x.z, x.z, x.w * x.w)));
  a += __shfl_xor(a, 1);  a += __shfl_xor(a, 2);  a += __shfl_xor(a, 4);
  a += __shfl_xor(a, 8);  a += __shfl_xor(a, 16); a += __shfl_xor(a, 32);
  __shared__ float red[4];
  if ((threadIdx.x & 63) == 0) red[threadIdx.x >> 6] = a;
  __syncthreads();
  if (threadIdx.x == 0)   { Xn[gr] = red[0] + red[1]; Vn[gr] = 0.f; }
  if (threadIdx.x == 128) { Xn[gr] = red[2] + red[3]; Vn[gr] = 0.f; }
}

// ---------------- proj_gemm: bf16x2-split MFMA GEMM + h_linear epilogue --------------
// C[128x128] per block; grid (32,4,3); acc = Xh@Zh + Xh@Zl + Xl@Zh (fp32 accumulate)
__global__ __launch_bounds__(256) void proj_gemm(
    const u16* __restrict__ Xh, const u16* __restrict__ Xl,
    const u16* __restrict__ ZhT, const u16* __restrict__ ZlT,
    const float* __restrict__ Xn, const float4* __restrict__ WM,
    float* __restrict__ Vtmp, float* __restrict__ Vn) {
  const int m0 = blockIdx.x * 128;
  const int n0 = blockIdx.y * 128;
  const int mat = blockIdx.z;
  const size_t xoff = (size_t)mat * 4096 * 512;
  const size_t zoff = (size_t)mat * 512 * 512;
  const int t = threadIdx.x, wv = t >> 6, lane = t & 63;
  const int l15 = lane & 15, quad = lane >> 4;

  __shared__ __align__(16) u16 Ah[128 * 32], Al[128 * 32], Bh[128 * 32], Bl[128 * 32];
  __shared__ float lams[128], lam1s[128], wmxs[128], wmys[128], wmzs[128];

  if (t < 128) {
    float x2 = Xn[mat * 4096 + m0 + t];
    float lam = 2.f / fmaxf(1.f - x2, EPSf);
    lams[t] = lam; lam1s[t] = lam - 1.f;
    float4 wm = WM[mat * 512 + n0 + t];
    wmxs[t] = wm.x; wmys[t] = wm.y; wmzs[t] = wm.z;
  }

  f32x4 acc[4][4];
  #pragma unroll
  for (int i = 0; i < 4; ++i)
    #pragma unroll
    for (int j = 0; j < 4; ++j) acc[i][j] = (f32x4){0.f, 0.f, 0.f, 0.f};

  const int srow = 32 * wv + (lane >> 2);
  const int scol = (lane & 3) * 8;
  const u16* gAh = Xh + xoff + (size_t)(m0 + srow) * 512 + scol;
  const u16* gAl = Xl + xoff + (size_t)(m0 + srow) * 512 + scol;
  const u16* gBh = ZhT + zoff + (size_t)(n0 + srow) * 512 + scol;
  const u16* gBl = ZlT + zoff + (size_t)(n0 + srow) * 512 + scol;

  for (int k0 = 0; k0 < 512; k0 += 32) {
    __syncthreads();
    gll16(gAh + k0,            &Ah[(32 * wv) * 32]);
    gll16(gAh + k0 + 16 * 512, &Ah[(32 * wv + 16) * 32]);
    gll16(gAl + k0,            &Al[(32 * wv) * 32]);
    gll16(gAl + k0 + 16 * 512, &Al[(32 * wv + 16) * 32]);
    gll16(gBh + k0,            &Bh[(32 * wv) * 32]);
    gll16(gBh + k0 + 16 * 512, &Bh[(32 * wv + 16) * 32]);
    gll16(gBl + k0,            &Bl[(32 * wv) * 32]);
    gll16(gBl + k0 + 16 * 512, &Bl[(32 * wv + 16) * 32]);
    __syncthreads();
    const int mh = (wv >> 1) * 64, nh = (wv & 1) * 64;
    bf16x8 ah[4], al[4], bh_[4], bl_[4];
    #pragma unroll
    for (int i = 0; i < 4; ++i) {
      int ra = mh + i * 16 + l15;
      ah[i] = *(const bf16x8*)&Ah[ra * 32 + quad * 8];
      al[i] = *(const bf16x8*)&Al[ra * 32 + quad * 8];
      int rb = nh + i * 16 + l15;
      bh_[i] = *(const bf16x8*)&Bh[rb * 32 + quad * 8];
      bl_[i] = *(const bf16x8*)&Bl[rb * 32 + quad * 8];
    }
    #pragma unroll
    for (int i = 0; i < 4; ++i)
      #pragma unroll
      for (int j = 0; j < 4; ++j) {
        acc[i][j] = __builtin_amdgcn_mfma_f32_16x16x32_bf16(ah[i], bh_[j], acc[i][j], 0, 0, 0);
        acc[i][j] = __builtin_amdgcn_mfma_f32_16x16x32_bf16(ah[i], bl_[j], acc[i][j], 0, 0, 0);
        acc[i][j] = __builtin_amdgcn_mfma_f32_16x16x32_bf16(al[i], bh_[j], acc[i][j], 0, 0, 0);
      }
  }

  // epilogue: v = 2*zn*asinh(lam*xz*cosh2r/zn - (lam-1)*sinh2r); row |v|^2 partials
  const int mh = (wv >> 1) * 64, nh = (wv & 1) * 64;
  #pragma unroll
  for (int i = 0; i < 4; ++i) {
    float rsum[4] = {0.f, 0.f, 0.f, 0.f};
    #pragma unroll
    for (int j = 0; j < 4; ++j) {
      int nl = nh + j * 16 + l15;
      float wx = wmxs[nl], wy = wmys[nl], wz = wmzs[nl];
      #pragma unroll
      for (int r = 0; r < 4; ++r) {
        int ml = mh + i * 16 + quad * 4 + r;
        float tt = lams[ml] * acc[i][j][r] * wx - lam1s[ml] * wy;
        float v = wz * logf(tt + sqrtf(fmaf(tt, tt, 1.f)));
        Vtmp[xoff + (size_t)(m0 + ml) * 512 + (n0 + nl)] = v;
        rsum[r] = fmaf(v, v, rsum[r]);
      }
    }
    #pragma unroll
    for (int r = 0; r < 4; ++r) {
      rsum[r] += __shfl_xor(rsum[r], 1);
      rsum[r] += __shfl_xor(rsum[r], 2);
      rsum[r] += __shfl_xor(rsum[r], 4);
      rsum[r] += __shfl_xor(rsum[r], 8);
    }
    if (l15 == 0) {
      #pragma unroll
      for (int r = 0; r < 4; ++r)
        atomicAdd(&Vn[mat * 4096 + m0 + mh + i * 16 + quad * 4 + r], rsum[r]);
    }
  }
}

// ---------------- attn: fused hyperbolic attention, MFMA both GEMMs ------------------
// grid (16 q-tiles, 32 bh), block 256. Stages ball-projected bf16 tiles from Vtmp/Vn;
// q2/k2/lam computed from the bf16-rounded staged values (consistent perturbation).
__global__ __launch_bounds__(256) void attn(
    const float* __restrict__ Vtmp, const float* __restrict__ Vn, float* __restrict__ out) {
  const int bh = blockIdx.y;
  const int b = bh >> 3, h = bh & 7;
  const int q0 = blockIdx.x * 64;
  const int t = threadIdx.x, wv = t >> 6, lane = t & 63;
  const int l15 = lane & 15, quad = lane >> 4;

  const float* Vq = Vtmp;
  const float* Vk = Vtmp + (size_t)4096 * 512;
  const float* Vv = Vtmp + (size_t)2 * 4096 * 512;
  const float* Nq = Vn;
  const float* Nk = Vn + 4096;
  const float* Nv = Vn + 8192;

  __shared__ __align__(16) u16 Qs[64 * 72], Ks[64 * 72], Vs[64 * 72], VsT[64 * 72], Ws[64 * 72];
  __shared__ float q2s[64], k2s[64], cks[64], lamvs[64], l1s[64], dens[64];

  // ---- stage Q (ball-scale, bf16) + q2 from rounded values ----
  {
    const int g = t & 7;
    #pragma unroll
    for (int p = 0; p < 2; ++p) {
      int q = (t >> 3) + 32 * p;
      int gi = b * 1024 + q0 + q;
      const float* src = Vq + (size_t)gi * 512 + h * 64 + g * 8;
      float4 xa = *(const float4*)(src);
      float4 xb = *(const float4*)(src + 4);
      float sc = 1.f / (1.f + sqrtf(1.f + Nq[gi]));
      u16 u0 = f2bf(xa.x * sc), u1 = f2bf(xa.y * sc), u2 = f2bf(xa.z * sc), u3 = f2bf(xa.w * sc);
      u16 u4 = f2bf(xb.x * sc), u5 = f2bf(xb.y * sc), u6 = f2bf(xb.z * sc), u7 = f2bf(xb.w * sc);
      *(ushort4*)&Qs[q * 72 + g * 8]     = make_ushort4(u0, u1, u2, u3);
      *(ushort4*)&Qs[q * 72 + g * 8 + 4] = make_ushort4(u4, u5, u6, u7);
      float f0 = bf2f(u0), f1 = bf2f(u1), f2 = bf2f(u2), f3 = bf2f(u3);
      float f4 = bf2f(u4), f5 = bf2f(u5), f6 = bf2f(u6), f7 = bf2f(u7);
      float ps = f0*f0 + f1*f1 + f2*f2 + f3*f3 + f4*f4 + f5*f5 + f6*f6 + f7*f7;
      ps += __shfl_xor(ps, 1); ps += __shfl_xor(ps, 2); ps += __shfl_xor(ps, 4);
      if (g == 0) q2s[q] = ps;
    }
  }
  __syncthreads();

  float q2r[4], aqr[4];
  #pragma unroll
  for (int r = 0; r < 4; ++r) {
    float q2 = q2s[16 * wv + 4 * quad + r];
    q2r[r] = q2;
    aqr[r] = 1.f / fmaxf(1.f - q2, EPSf);
  }
  // hoist Q fragments (constant over kt)
  bf16x8 qf0 = *(const bf16x8*)&Qs[(16 * wv + l15) * 72 + quad * 8];
  bf16x8 qf1 = *(const bf16x8*)&Qs[(16 * wv + l15) * 72 + 32 + quad * 8];

  f32x4 num[4];
  #pragma unroll
  for (int i = 0; i < 4; ++i) num[i] = (f32x4){0.f, 0.f, 0.f, 0.f};
  float denp[4] = {0.f, 0.f, 0.f, 0.f};

  for (int kt = 0; kt < 16; ++kt) {
    __syncthreads();  // previous iteration done with Ks/Vs/VsT
    // ---- stage K and V rows (bf16, ball-scaled); k2/lam from rounded values ----
    {
      const int g = t & 7;
      #pragma unroll
      for (int p = 0; p < 2; ++p) {
        int k = (t >> 3) + 32 * p;
        int gi = b * 1024 + kt * 64 + k;
        // K
        {
          const float* src = Vk + (size_t)gi * 512 + h * 64 + g * 8;
          float4 xa = *(const float4*)(src);
          float4 xb = *(const float4*)(src + 4);
          float sc = 1.f / (1.f + sqrtf(1.f + Nk[gi]));
          u16 u0 = f2bf(xa.x*sc), u1 = f2bf(xa.y*sc), u2 = f2bf(xa.z*sc), u3 = f2bf(xa.w*sc);
          u16 u4 = f2bf(xb.x*sc), u5 = f2bf(xb.y*sc), u6 = f2bf(xb.z*sc), u7 = f2bf(xb.w*sc);
          *(ushort4*)&Ks[k * 72 + g * 8]     = make_ushort4(u0, u1, u2, u3);
          *(ushort4*)&Ks[k * 72 + g * 8 + 4] = make_ushort4(u4, u5, u6, u7);
          float f0 = bf2f(u0), f1 = bf2f(u1), f2 = bf2f(u2), f3 = bf2f(u3);
          float f4 = bf2f(u4), f5 = bf2f(u5), f6 = bf2f(u6), f7 = bf2f(u7);
          float ps = f0*f0 + f1*f1 + f2*f2 + f3*f3 + f4*f4 + f5*f5 + f6*f6 + f7*f7;
          ps += __shfl_xor(ps, 1); ps += __shfl_xor(ps, 2); ps += __shfl_xor(ps, 4);
          if (g == 0) { k2s[k] = ps; cks[k] = 2.f / fmaxf(1.f - ps, EPSf); }
        }
        // V (raw ball-scaled bf16; lambda applied in transpose)
        {
          const float* src = Vv + (size_t)gi * 512 + h * 64 + g * 8;
          float4 xa = *(const float4*)(src);
          float4 xb = *(const float4*)(src + 4);
          float sc = 1.f / (1.f + sqrtf(1.f + Nv[gi]));
          u16 u0 = f2bf(xa.x*sc), u1 = f2bf(xa.y*sc), u2 = f2bf(xa.z*sc), u3 = f2bf(xa.w*sc);
          u16 u4 = f2bf(xb.x*sc), u5 = f2bf(xb.y*sc), u6 = f2bf(xb.z*sc), u7 = f2bf(xb.w*sc);
          *(ushort4*)&Vs[k * 72 + g * 8]     = make_ushort4(u0, u1, u2, u3);
          *(ushort4*)&Vs[k * 72 + g * 8 + 4] = make_ushort4(u4, u5, u6, u7);
          float f0 = bf2f(u0), f1 = bf2f(u1), f2 = bf2f(u2), f3 = bf2f(u3);
          float f4 = bf2f(u4), f5 = bf2f(u5), f6 = bf2f(u6), f7 = bf2f(u7);
          float ps = f0*f0 + f1*f1 + f2*f2 + f3*f3 + f4*f4 + f5*f5 + f6*f6 + f7*f7;
          ps += __shfl_xor(ps, 1); ps += __shfl_xor(ps, 2); ps += __shfl_xor(ps, 4);
          if (g == 0) {
            float lam = 2.f / fmaxf(1.f - ps, EPSf);
            lamvs[k] = lam; l1s[k] = lam - 1.f;
          }
        }
      }
    }
    // ---- transpose: VsT[d][k] = bf16(lam_k * Vs[k][d])  (wave-local rows) ----
    #pragma unroll
    for (int p2 = 0; p2 < 2; ++p2) {
      int d = lane;
      int kg = wv + 4 * p2;
      u16 uu[8];
      #pragma unroll
      for (int j = 0; j < 8; ++j) {
        int k = kg * 8 + j;
        uu[j] = f2bf(bf2f(Vs[k * 72 + d]) * lamvs[k]);
      }
      *(ushort4*)&VsT[d * 72 + kg * 8]     = make_ushort4(uu[0], uu[1], uu[2], uu[3]);
      *(ushort4*)&VsT[d * 72 + kg * 8 + 4] = make_ushort4(uu[4], uu[5], uu[6], uu[7]);
    }
    __syncthreads();  // K/V/VsT/scalars visible to all waves

    // ---- phase A: scores = Q K^T (64x64, contraction d=64) ----
    f32x4 sc_[4];
    #pragma unroll
    for (int tn = 0; tn < 4; ++tn) {
      bf16x8 kf0 = *(const bf16x8*)&Ks[(16 * tn + l15) * 72 + quad * 8];
      bf16x8 kf1 = *(const bf16x8*)&Ks[(16 * tn + l15) * 72 + 32 + quad * 8];
      f32x4 s = (f32x4){0.f, 0.f, 0.f, 0.f};
      s = __builtin_amdgcn_mfma_f32_16x16x32_bf16(qf0, kf0, s, 0, 0, 0);
      s = __builtin_amdgcn_mfma_f32_16x16x32_bf16(qf1, kf1, s, 0, 0, 0);
      sc_[tn] = s;
    }
    // ---- weight chain: w = (1+u) - sqrt(u(u+2)), u = 2*diff2/((1-q2)(1-k2)) ----
    #pragma unroll
    for (int tn = 0; tn < 4; ++tn) {
      int kidx = 16 * tn + l15;
      float k2 = k2s[kidx], ck = cks[kidx], l1f = l1s[kidx];
      u16 wu[4];
      #pragma unroll
      for (int r = 0; r < 4; ++r) {
        float d2 = fmaxf(fmaf(-2.f, sc_[tn][r], q2r[r] + k2), 0.f);
        float u = fmaxf(d2 * ck * aqr[r], EPSf);
        float s2 = sqrtf(u * (u + 2.f));
        float w = (1.f + u) - s2;
        u16 wb = f2bf(w);
        wu[r] = wb;
        denp[r] = fmaf(bf2f(wb), l1f, denp[r]);
      }
      #pragma unroll
      for (int r = 0; r < 4; ++r)
        Ws[(16 * wv + 4 * quad + r) * 72 + kidx] = wu[r];
    }
    // ---- phase B: num[d][q] += V^T W^T  (A=VsT, B=Ws rows; wave-private Ws) ----
    #pragma unroll
    for (int ks = 0; ks < 2; ++ks) {
      bf16x8 wf = *(const bf16x8*)&Ws[(16 * wv + l15) * 72 + ks * 32 + quad * 8];
      #pragma unroll
      for (int tm = 0; tm < 4; ++tm) {
        bf16x8 vf = *(const bf16x8*)&VsT[(16 * tm + l15) * 72 + ks * 32 + quad * 8];
        num[tm] = __builtin_amdgcn_mfma_f32_16x16x32_bf16(vf, wf, num[tm], 0, 0, 0);
      }
    }
  }

  // ---- epilogue: midpoint + half mobius scalar-mul ----
  #pragma unroll
  for (int r = 0; r < 4; ++r) {
    denp[r] += __shfl_xor(denp[r], 1);
    denp[r] += __shfl_xor(denp[r], 2);
    denp[r] += __shfl_xor(denp[r], 4);
    denp[r] += __shfl_xor(denp[r], 8);
  }
  if (l15 < 4) {
    float dv = (l15 == 0) ? denp[0] : (l15 == 1) ? denp[1] : (l15 == 2) ? denp[2] : denp[3];
    dens[16 * wv + 4 * quad + l15] = dv;
  }
  // wave-private rows of dens: LDS ops in-order within wave, no barrier needed
  float den = dens[16 * wv + l15];
  den = (fabsf(den) < EPSf) ? EPSf : den;
  float inv = 1.f / den;
  float mv[4][4];
  float p = 0.f;
  #pragma unroll
  for (int tm = 0; tm < 4; ++tm)
    #pragma unroll
    for (int r = 0; r < 4; ++r) {
      float m = num[tm][r] * inv;
      mv[tm][r] = m;
      p = fmaf(m, m, p);
    }
  p += __shfl_xor(p, 16);
  p += __shfl_xor(p, 32);
  float mn = sqrtf(p);
  float mnc = fmaxf(mn, EPSf);
  float tt2 = fminf(mnc, 1.f - 1e-6f);
  float scale = tt2 / ((1.f + sqrtf(fmaxf(1.f - tt2 * tt2, 0.f))) * mnc);
  const int qg = b * 1024 + q0 + 16 * wv + l15;
  #pragma unroll
  for (int tm = 0; tm < 4; ++tm) {
    float4 o = make_float4(mv[tm][0] * scale, mv[tm][1] * scale, mv[tm][2] * scale, mv[tm][3] * scale);
    *(float4*)(out + (size_t)qg * 512 + h * 64 + tm * 16 + quad * 4) = o;
  }
}

// ---------------- host ----------------
extern "C" void kernel_launch(void* const* d_in, const int* in_sizes, int n_in,
                              void* d_out, int out_size, void* d_ws, size_t ws_size,
                              hipStream_t stream) {
  (void)in_sizes; (void)n_in; (void)out_size; (void)ws_size;
  const float* q  = (const float*)d_in[0];
  const float* k  = (const float*)d_in[1];
  const float* v  = (const float*)d_in[2];
  const float* zq = (const float*)d_in[3];
  const float* rq = (const float*)d_in[4];
  const float* zk = (const float*)d_in[5];
  const float* rk = (const float*)d_in[6];
  const float* zv = (const float*)d_in[7];
  const float* rv = (const float*)d_in[8];

  unsigned char* ws = (unsigned char*)d_ws;
  // ws layout (bytes):
  u16*   Xh   = (u16*)(ws + 0);          // 3*4096*512*2 = 12582912
  u16*   Xl   = (u16*)(ws + 12582912);   // 12582912
  u16*   ZhT  = (u16*)(ws + 25165824);   // 1572864
  u16*   ZlT  = (u16*)(ws + 26738688);   // 1572864
  float* Vtmp = (float*)(ws + 28311552); // 25165824
  float* Xn   = (float*)(ws + 53477376); // 49152
  float* Vn   = (float*)(ws + 53526528); // 49152
  float4* WM  = (float4*)(ws + 53575680);// 24576   -> total ~53.6 MB

  split_z<<<24, 256, 0, stream>>>(zq, zk, zv, rq, rk, rv, ZhT, ZlT, WM);
  split_x<<<6144, 256, 0, stream>>>(q, k, v, Xh, Xl, Xn, Vn);
  proj_gemm<<<dim3(32, 4, 3), 256, 0, stream>>>(Xh, Xl, ZhT, ZlT, Xn, WM, Vtmp, Vn);
  attn<<<dim3(16, 32), 256, 0, stream>>>(Vtmp, Vn, (float*)d_out);
}

// Round 3
// 190.974 us; speedup vs baseline: 2.0147x; 1.1413x over previous
//
#include <hip/hip_runtime.h>
#include <math.h>

#define EPSf 1e-7f
typedef unsigned short u16;
typedef __attribute__((ext_vector_type(8))) short bf16x8;
typedef __attribute__((ext_vector_type(4))) float f32x4;

__device__ __forceinline__ float bf2f(u16 u) {
  union { unsigned int i; float f; } x; x.i = ((unsigned int)u) << 16; return x.f;
}
__device__ __forceinline__ u16 f2bf(float f) {  // RNE
  union { float f; unsigned int i; } x; x.f = f;
  unsigned int r = x.i + 0x7fffu + ((x.i >> 16) & 1u);
  return (u16)(r >> 16);
}
__device__ __forceinline__ void gll16(const void* g, void* l) {
  __builtin_amdgcn_global_load_lds((__attribute__((address_space(1))) void*)(g),
                                   (__attribute__((address_space(3))) void*)(l),
                                   16, 0, 0);
}

// ---------------- split_z: z -> ZhT/ZlT (transposed bf16 hi/lo) + col norms -> WM ----
__global__ __launch_bounds__(256) void split_z(
    const float* __restrict__ zq, const float* __restrict__ zk, const float* __restrict__ zv,
    const float* __restrict__ rq, const float* __restrict__ rk, const float* __restrict__ rv,
    u16* __restrict__ ZhT, u16* __restrict__ ZlT, float4* __restrict__ WM) {
  const int mat = blockIdx.x >> 3;
  const int c0 = (blockIdx.x & 7) * 64;
  const float* Z = (mat == 0) ? zq : (mat == 1) ? zk : zv;
  const float* R = (mat == 0) ? rq : (mat == 1) ? rk : rv;
  __shared__ float tile[64][68];
  const int t = threadIdx.x;
  const int cl = t >> 2, kg4 = t & 3;
  const size_t zo = (size_t)mat * 512 * 512;
  float csum = 0.f;
  for (int kt = 0; kt < 8; ++kt) {
    __syncthreads();
    {
      int kl = t >> 2;
      const float* src = Z + (size_t)(kt * 64 + kl) * 512 + c0;
      #pragma unroll
      for (int j = 0; j < 4; ++j) {
        float4 v = *(const float4*)(src + (t & 3) * 16 + 4 * j);
        *(float4*)&tile[kl][(t & 3) * 16 + 4 * j] = v;
      }
    }
    __syncthreads();
    #pragma unroll
    for (int jj = 0; jj < 4; ++jj) {
      u16 hb[4], lb[4];
      #pragma unroll
      for (int qq = 0; qq < 4; ++qq) {
        float zval = tile[kg4 * 16 + jj * 4 + qq][cl];
        csum = fmaf(zval, zval, csum);
        u16 hh = f2bf(zval);
        hb[qq] = hh;
        lb[qq] = f2bf(zval - bf2f(hh));
      }
      size_t o = zo + (size_t)(c0 + cl) * 512 + kt * 64 + kg4 * 16 + jj * 4;
      *(ushort4*)(ZhT + o) = make_ushort4(hb[0], hb[1], hb[2], hb[3]);
      *(ushort4*)(ZlT + o) = make_ushort4(lb[0], lb[1], lb[2], lb[3]);
    }
  }
  csum += __shfl_xor(csum, 1);
  csum += __shfl_xor(csum, 2);
  if (kg4 == 0) {
    float zn = fmaxf(sqrtf(csum), EPSf);
    float tr = 2.f * R[c0 + cl];
    float e = expf(tr), ei = 1.f / e;
    WM[mat * 512 + c0 + cl] = make_float4(0.5f * (e + ei) / zn, 0.5f * (e - ei), 2.f * zn, 0.f);
  }
}

// ---------------- split_x: x -> Xh/Xl bf16 planes + row norms Xn + zero Vn ------------
__global__ __launch_bounds__(256) void split_x(
    const float* __restrict__ xq, const float* __restrict__ xk, const float* __restrict__ xv,
    u16* __restrict__ Xh, u16* __restrict__ Xl,
    float* __restrict__ Xn, float* __restrict__ Vn) {
  const int gr = blockIdx.x * 2 + (threadIdx.x >> 7);
  const int mat = gr >> 12, row = gr & 4095;
  const float* X = (mat == 0) ? xq : (mat == 1) ? xk : xv;
  const int f4 = threadIdx.x & 127;
  float4 x = ((const float4*)(X + (size_t)row * 512))[f4];
  u16 h0 = f2bf(x.x), h1 = f2bf(x.y), h2 = f2bf(x.z), h3 = f2bf(x.w);
  u16 l0 = f2bf(x.x - bf2f(h0)), l1 = f2bf(x.y - bf2f(h1));
  u16 l2 = f2bf(x.z - bf2f(h2)), l3 = f2bf(x.w - bf2f(h3));
  ((ushort4*)(Xh + (size_t)gr * 512))[f4] = make_ushort4(h0, h1, h2, h3);
  ((ushort4*)(Xl + (size_t)gr * 512))[f4] = make_ushort4(l0, l1, l2, l3);
  float a = fmaf(x.x, x.x, fmaf(x.y, x.y, fmaf(x.z, x.z, x.w * x.w)));
  a += __shfl_xor(a, 1);  a += __shfl_xor(a, 2);  a += __shfl_xor(a, 4);
  a += __shfl_xor(a, 8);  a += __shfl_xor(a, 16); a += __shfl_xor(a, 32);
  __shared__ float red[4];
  if ((threadIdx.x & 63) == 0) red[threadIdx.x >> 6] = a;
  __syncthreads();
  if (threadIdx.x == 0)   { Xn[gr] = red[0] + red[1]; Vn[gr] = 0.f; }
  if (threadIdx.x == 128) { Xn[gr] = red[2] + red[3]; Vn[gr] = 0.f; }
}

// ---------------- proj_gemm: bf16x2-split MFMA GEMM + h_linear epilogue --------------
__global__ __launch_bounds__(256) void proj_gemm(
    const u16* __restrict__ Xh, const u16* __restrict__ Xl,
    const u16* __restrict__ ZhT, const u16* __restrict__ ZlT,
    const float* __restrict__ Xn, const float4* __restrict__ WM,
    float* __restrict__ Vtmp, float* __restrict__ Vn) {
  const int m0 = blockIdx.x * 128;
  const int n0 = blockIdx.y * 128;
  const int mat = blockIdx.z;
  const size_t xoff = (size_t)mat * 4096 * 512;
  const size_t zoff = (size_t)mat * 512 * 512;
  const int t = threadIdx.x, wv = t >> 6, lane = t & 63;
  const int l15 = lane & 15, quad = lane >> 4;

  __shared__ __align__(16) u16 Ah[128 * 32], Al[128 * 32], Bh[128 * 32], Bl[128 * 32];
  __shared__ float lams[128], lam1s[128], wmxs[128], wmys[128], wmzs[128];

  if (t < 128) {
    float x2 = Xn[mat * 4096 + m0 + t];
    float lam = 2.f / fmaxf(1.f - x2, EPSf);
    lams[t] = lam; lam1s[t] = lam - 1.f;
    float4 wm = WM[mat * 512 + n0 + t];
    wmxs[t] = wm.x; wmys[t] = wm.y; wmzs[t] = wm.z;
  }

  f32x4 acc[4][4];
  #pragma unroll
  for (int i = 0; i < 4; ++i)
    #pragma unroll
    for (int j = 0; j < 4; ++j) acc[i][j] = (f32x4){0.f, 0.f, 0.f, 0.f};

  const int srow = 32 * wv + (lane >> 2);
  const int scol = (lane & 3) * 8;
  const u16* gAh = Xh + xoff + (size_t)(m0 + srow) * 512 + scol;
  const u16* gAl = Xl + xoff + (size_t)(m0 + srow) * 512 + scol;
  const u16* gBh = ZhT + zoff + (size_t)(n0 + srow) * 512 + scol;
  const u16* gBl = ZlT + zoff + (size_t)(n0 + srow) * 512 + scol;

  for (int k0 = 0; k0 < 512; k0 += 32) {
    __syncthreads();
    gll16(gAh + k0,            &Ah[(32 * wv) * 32]);
    gll16(gAh + k0 + 16 * 512, &Ah[(32 * wv + 16) * 32]);
    gll16(gAl + k0,            &Al[(32 * wv) * 32]);
    gll16(gAl + k0 + 16 * 512, &Al[(32 * wv + 16) * 32]);
    gll16(gBh + k0,            &Bh[(32 * wv) * 32]);
    gll16(gBh + k0 + 16 * 512, &Bh[(32 * wv + 16) * 32]);
    gll16(gBl + k0,            &Bl[(32 * wv) * 32]);
    gll16(gBl + k0 + 16 * 512, &Bl[(32 * wv + 16) * 32]);
    __syncthreads();
    const int mh = (wv >> 1) * 64, nh = (wv & 1) * 64;
    bf16x8 ah[4], al[4], bh_[4], bl_[4];
    #pragma unroll
    for (int i = 0; i < 4; ++i) {
      int ra = mh + i * 16 + l15;
      ah[i] = *(const bf16x8*)&Ah[ra * 32 + quad * 8];
      al[i] = *(const bf16x8*)&Al[ra * 32 + quad * 8];
      int rb = nh + i * 16 + l15;
      bh_[i] = *(const bf16x8*)&Bh[rb * 32 + quad * 8];
      bl_[i] = *(const bf16x8*)&Bl[rb * 32 + quad * 8];
    }
    #pragma unroll
    for (int i = 0; i < 4; ++i)
      #pragma unroll
      for (int j = 0; j < 4; ++j) {
        acc[i][j] = __builtin_amdgcn_mfma_f32_16x16x32_bf16(ah[i], bh_[j], acc[i][j], 0, 0, 0);
        acc[i][j] = __builtin_amdgcn_mfma_f32_16x16x32_bf16(ah[i], bl_[j], acc[i][j], 0, 0, 0);
        acc[i][j] = __builtin_amdgcn_mfma_f32_16x16x32_bf16(al[i], bh_[j], acc[i][j], 0, 0, 0);
      }
  }

  const int mh = (wv >> 1) * 64, nh = (wv & 1) * 64;
  #pragma unroll
  for (int i = 0; i < 4; ++i) {
    float rsum[4] = {0.f, 0.f, 0.f, 0.f};
    #pragma unroll
    for (int j = 0; j < 4; ++j) {
      int nl = nh + j * 16 + l15;
      float wx = wmxs[nl], wy = wmys[nl], wz = wmzs[nl];
      #pragma unroll
      for (int r = 0; r < 4; ++r) {
        int ml = mh + i * 16 + quad * 4 + r;
        float tt = lams[ml] * acc[i][j][r] * wx - lam1s[ml] * wy;
        float v = wz * logf(tt + sqrtf(fmaf(tt, tt, 1.f)));
        Vtmp[xoff + (size_t)(m0 + ml) * 512 + (n0 + nl)] = v;
        rsum[r] = fmaf(v, v, rsum[r]);
      }
    }
    #pragma unroll
    for (int r = 0; r < 4; ++r) {
      rsum[r] += __shfl_xor(rsum[r], 1);
      rsum[r] += __shfl_xor(rsum[r], 2);
      rsum[r] += __shfl_xor(rsum[r], 4);
      rsum[r] += __shfl_xor(rsum[r], 8);
    }
    if (l15 == 0) {
      #pragma unroll
      for (int r = 0; r < 4; ++r)
        atomicAdd(&Vn[mat * 4096 + m0 + mh + i * 16 + quad * 4 + r], rsum[r]);
    }
  }
}

// ---------------- pack_qk: ball-scale + bf16 + head-major relayout + scalars ---------
// grid 256 (2 mats x 128 row-blocks of 32), block 256: thread = (row, head)
__global__ __launch_bounds__(256) void pack_qk(
    const float* __restrict__ Vtmp, const float* __restrict__ Vn,
    u16* __restrict__ Qh, u16* __restrict__ Kh,
    float* __restrict__ q2a, float* __restrict__ aqa,
    float* __restrict__ k2a, float* __restrict__ cka) {
  const int mat = blockIdx.x >> 7;       // 0=Q, 1=K
  const int rb = blockIdx.x & 127;
  const int r = threadIdx.x >> 3;
  const int h = threadIdx.x & 7;
  const int row = rb * 32 + r;
  const size_t gr = (size_t)mat * 4096 + row;
  const float sc = 1.f / (1.f + sqrtf(1.f + Vn[gr]));
  const float* src = Vtmp + gr * 512 + h * 64;
  const int b = row >> 10, s = row & 1023;
  u16* dst = (mat ? Kh : Qh) + ((size_t)(b * 8 + h) * 1024 + s) * 64;
  float nrm = 0.f;
  #pragma unroll
  for (int j = 0; j < 16; ++j) {
    float4 x = *(const float4*)(src + 4 * j);
    u16 u0 = f2bf(x.x * sc), u1 = f2bf(x.y * sc), u2 = f2bf(x.z * sc), u3 = f2bf(x.w * sc);
    *(ushort4*)(dst + 4 * j) = make_ushort4(u0, u1, u2, u3);
    float f0 = bf2f(u0), f1 = bf2f(u1), f2 = bf2f(u2), f3 = bf2f(u3);
    nrm += f0 * f0 + f1 * f1 + f2 * f2 + f3 * f3;
  }
  const size_t so = (size_t)(b * 8 + h) * 1024 + s;
  if (mat == 0) { q2a[so] = nrm; aqa[so] = 1.f / fmaxf(1.f - nrm, EPSf); }
  else          { k2a[so] = nrm; cka[so] = 2.f / fmaxf(1.f - nrm, EPSf); }
}

// ---------------- pack_v: ball-scale + bf16 + transpose to [b,h,d,s] with lam folded --
// grid 512 (= 32 bh x 16 s-tiles), block 256
__global__ __launch_bounds__(256) void pack_v(
    const float* __restrict__ Vtmp, const float* __restrict__ Vn,
    u16* __restrict__ VTb, float* __restrict__ l1a) {
  const int bh = blockIdx.x >> 4;
  const int st = blockIdx.x & 15;
  const int b = bh >> 3, h = bh & 7;
  __shared__ u16 tile[64][72];
  __shared__ float lams[64];
  const int t = threadIdx.x;
  {
    const int s = t >> 2, dg = t & 3;
    const size_t gr = (size_t)2 * 4096 + b * 1024 + st * 64 + s;
    const float sc = 1.f / (1.f + sqrtf(1.f + Vn[gr]));
    const float* src = Vtmp + gr * 512 + h * 64 + dg * 16;
    float nrm = 0.f;
    #pragma unroll
    for (int j = 0; j < 4; ++j) {
      float4 x = *(const float4*)(src + 4 * j);
      u16 u0 = f2bf(x.x * sc), u1 = f2bf(x.y * sc), u2 = f2bf(x.z * sc), u3 = f2bf(x.w * sc);
      *(ushort4*)&tile[s][dg * 16 + 4 * j] = make_ushort4(u0, u1, u2, u3);
      float f0 = bf2f(u0), f1 = bf2f(u1), f2 = bf2f(u2), f3 = bf2f(u3);
      nrm += f0 * f0 + f1 * f1 + f2 * f2 + f3 * f3;
    }
    nrm += __shfl_xor(nrm, 1);
    nrm += __shfl_xor(nrm, 2);
    if (dg == 0) {
      float lam = 2.f / fmaxf(1.f - nrm, EPSf);
      lams[s] = lam;
      l1a[(size_t)bh * 1024 + st * 64 + s] = lam - 1.f;
    }
  }
  __syncthreads();
  const int d = t >> 2, sg = t & 3;
  u16 ob[16];
  #pragma unroll
  for (int j = 0; j < 16; ++j) {
    int ss = sg * 16 + j;
    ob[j] = f2bf(bf2f(tile[ss][d]) * lams[ss]);
  }
  u16* dst = VTb + ((size_t)bh * 64 + d) * 1024 + st * 64 + sg * 16;
  #pragma unroll
  for (int j = 0; j < 4; ++j)
    *(ushort4*)(dst + 4 * j) = make_ushort4(ob[4 * j], ob[4 * j + 1], ob[4 * j + 2], ob[4 * j + 3]);
}

// ---------------- attn: fused hyperbolic attention, pre-packed bf16 inputs -----------
// grid (16 q-tiles, 32 bh), block 256
__global__ __launch_bounds__(256) void attn(
    const u16* __restrict__ Qh, const u16* __restrict__ Kh, const u16* __restrict__ VTb,
    const float* __restrict__ q2a, const float* __restrict__ aqa,
    const float* __restrict__ k2a, const float* __restrict__ cka,
    const float* __restrict__ l1a, float* __restrict__ out) {
  const int bh = blockIdx.y;
  const int b = bh >> 3, h = bh & 7;
  const int q0 = blockIdx.x * 64;
  const int t = threadIdx.x, wv = t >> 6, lane = t & 63;
  const int l15 = lane & 15, quad = lane >> 4;

  __shared__ __align__(16) u16 Qs[64 * 72], Ks[64 * 72], VsT[64 * 72], Ws[64 * 72];
  __shared__ float k2s[64], cks[64], l1s[64], dens[64];

  // stage Q (pre-scaled bf16, head-major)
  #pragma unroll
  for (int i = 0; i < 2; ++i) {
    int f = t + 256 * i;
    int row = f >> 3, g = f & 7;
    float4 v = *(const float4*)(Qh + ((size_t)bh * 1024 + q0 + row) * 64 + g * 8);
    *(float4*)&Qs[row * 72 + g * 8] = v;
  }
  float q2r[4], aqr[4];
  #pragma unroll
  for (int r = 0; r < 4; ++r) {
    int qi = bh * 1024 + q0 + 16 * wv + 4 * quad + r;
    q2r[r] = q2a[qi];
    aqr[r] = aqa[qi];
  }
  __syncthreads();
  const bf16x8 qf0 = *(const bf16x8*)&Qs[(16 * wv + l15) * 72 + quad * 8];
  const bf16x8 qf1 = *(const bf16x8*)&Qs[(16 * wv + l15) * 72 + 32 + quad * 8];

  f32x4 num[4];
  #pragma unroll
  for (int i = 0; i < 4; ++i) num[i] = (f32x4){0.f, 0.f, 0.f, 0.f};
  float denp[4] = {0.f, 0.f, 0.f, 0.f};

  for (int kt = 0; kt < 16; ++kt) {
    __syncthreads();  // previous iteration done with Ks/VsT
    #pragma unroll
    for (int i = 0; i < 2; ++i) {
      int f = t + 256 * i;
      int row = f >> 3, g = f & 7;
      float4 kv = *(const float4*)(Kh + ((size_t)bh * 1024 + kt * 64 + row) * 64 + g * 8);
      *(float4*)&Ks[row * 72 + g * 8] = kv;
      float4 vv = *(const float4*)(VTb + ((size_t)bh * 64 + row) * 1024 + kt * 64 + g * 8);
      *(float4*)&VsT[row * 72 + g * 8] = vv;
    }
    if (t < 64) {
      int ki = bh * 1024 + kt * 64 + t;
      k2s[t] = k2a[ki]; cks[t] = cka[ki]; l1s[t] = l1a[ki];
    }
    __syncthreads();

    // phase A: scores = Q K^T
    f32x4 sc_[4];
    #pragma unroll
    for (int tn = 0; tn < 4; ++tn) {
      bf16x8 kf0 = *(const bf16x8*)&Ks[(16 * tn + l15) * 72 + quad * 8];
      bf16x8 kf1 = *(const bf16x8*)&Ks[(16 * tn + l15) * 72 + 32 + quad * 8];
      f32x4 s = (f32x4){0.f, 0.f, 0.f, 0.f};
      s = __builtin_amdgcn_mfma_f32_16x16x32_bf16(qf0, kf0, s, 0, 0, 0);
      s = __builtin_amdgcn_mfma_f32_16x16x32_bf16(qf1, kf1, s, 0, 0, 0);
      sc_[tn] = s;
    }
    // weight chain: w = (1+u) - sqrt(u(u+2)), u = 2*diff2/((1-q2)(1-k2))
    #pragma unroll
    for (int tn = 0; tn < 4; ++tn) {
      int kidx = 16 * tn + l15;
      float k2 = k2s[kidx], ck = cks[kidx], l1f = l1s[kidx];
      u16 wu[4];
      #pragma unroll
      for (int r = 0; r < 4; ++r) {
        float d2 = fmaxf(fmaf(-2.f, sc_[tn][r], q2r[r] + k2), 0.f);
        float u = fmaxf(d2 * ck * aqr[r], EPSf);
        float s2 = sqrtf(u * (u + 2.f));
        float w = (1.f + u) - s2;
        u16 wb = f2bf(w);
        wu[r] = wb;
        denp[r] = fmaf(bf2f(wb), l1f, denp[r]);
      }
      #pragma unroll
      for (int r = 0; r < 4; ++r)
        Ws[(16 * wv + 4 * quad + r) * 72 + kidx] = wu[r];
    }
    // phase B: num[d][q] += V^T W^T (wave-private Ws rows, no barrier needed)
    #pragma unroll
    for (int ks = 0; ks < 2; ++ks) {
      bf16x8 wf = *(const bf16x8*)&Ws[(16 * wv + l15) * 72 + ks * 32 + quad * 8];
      #pragma unroll
      for (int tm = 0; tm < 4; ++tm) {
        bf16x8 vf = *(const bf16x8*)&VsT[(16 * tm + l15) * 72 + ks * 32 + quad * 8];
        num[tm] = __builtin_amdgcn_mfma_f32_16x16x32_bf16(vf, wf, num[tm], 0, 0, 0);
      }
    }
  }

  // epilogue: midpoint + half mobius scalar-mul
  #pragma unroll
  for (int r = 0; r < 4; ++r) {
    denp[r] += __shfl_xor(denp[r], 1);
    denp[r] += __shfl_xor(denp[r], 2);
    denp[r] += __shfl_xor(denp[r], 4);
    denp[r] += __shfl_xor(denp[r], 8);
  }
  if (l15 < 4) {
    float dv = (l15 == 0) ? denp[0] : (l15 == 1) ? denp[1] : (l15 == 2) ? denp[2] : denp[3];
    dens[16 * wv + 4 * quad + l15] = dv;
  }
  float den = dens[16 * wv + l15];
  den = (fabsf(den) < EPSf) ? EPSf : den;
  float inv = 1.f / den;
  float mv[4][4];
  float p = 0.f;
  #pragma unroll
  for (int tm = 0; tm < 4; ++tm)
    #pragma unroll
    for (int r = 0; r < 4; ++r) {
      float m = num[tm][r] * inv;
      mv[tm][r] = m;
      p = fmaf(m, m, p);
    }
  p += __shfl_xor(p, 16);
  p += __shfl_xor(p, 32);
  float mn = sqrtf(p);
  float mnc = fmaxf(mn, EPSf);
  float tt2 = fminf(mnc, 1.f - 1e-6f);
  float scale = tt2 / ((1.f + sqrtf(fmaxf(1.f - tt2 * tt2, 0.f))) * mnc);
  const int qg = b * 1024 + q0 + 16 * wv + l15;
  #pragma unroll
  for (int tm = 0; tm < 4; ++tm) {
    float4 o = make_float4(mv[tm][0] * scale, mv[tm][1] * scale, mv[tm][2] * scale, mv[tm][3] * scale);
    *(float4*)(out + (size_t)qg * 512 + h * 64 + tm * 16 + quad * 4) = o;
  }
}

// ---------------- host ----------------
extern "C" void kernel_launch(void* const* d_in, const int* in_sizes, int n_in,
                              void* d_out, int out_size, void* d_ws, size_t ws_size,
                              hipStream_t stream) {
  (void)in_sizes; (void)n_in; (void)out_size; (void)ws_size;
  const float* q  = (const float*)d_in[0];
  const float* k  = (const float*)d_in[1];
  const float* v  = (const float*)d_in[2];
  const float* zq = (const float*)d_in[3];
  const float* rq = (const float*)d_in[4];
  const float* zk = (const float*)d_in[5];
  const float* rk = (const float*)d_in[6];
  const float* zv = (const float*)d_in[7];
  const float* rv = (const float*)d_in[8];

  unsigned char* ws = (unsigned char*)d_ws;
  // phase-1 region (consumed by proj_gemm):
  u16*   Xh   = (u16*)(ws + 0);          // 12582912
  u16*   Xl   = (u16*)(ws + 12582912);   // 12582912
  u16*   ZhT  = (u16*)(ws + 25165824);   // 1572864
  u16*   ZlT  = (u16*)(ws + 26738688);   // 1572864
  float* Vtmp = (float*)(ws + 28311552); // 25165824
  float* Xn   = (float*)(ws + 53477376); // 49152
  float* Vn   = (float*)(ws + 53526528); // 49152
  float4* WM  = (float4*)(ws + 53575680);// 24576  -> end 53600256 (~53.6 MB)
  // phase-2 packed arrays overlap the dead Xh/Xl region (proj_gemm already done):
  u16*   Qh   = (u16*)(ws + 0);          // 4194304
  u16*   Kh   = (u16*)(ws + 4194304);    // 4194304
  u16*   VTb  = (u16*)(ws + 8388608);    // 4194304
  float* q2a  = (float*)(ws + 12582912); // 131072
  float* aqa  = (float*)(ws + 12713984); // 131072
  float* k2a  = (float*)(ws + 12845056); // 131072
  float* cka  = (float*)(ws + 12976128); // 131072
  float* l1a  = (float*)(ws + 13107200); // 131072

  split_z<<<24, 256, 0, stream>>>(zq, zk, zv, rq, rk, rv, ZhT, ZlT, WM);
  split_x<<<6144, 256, 0, stream>>>(q, k, v, Xh, Xl, Xn, Vn);
  proj_gemm<<<dim3(32, 4, 3), 256, 0, stream>>>(Xh, Xl, ZhT, ZlT, Xn, WM, Vtmp, Vn);
  pack_qk<<<256, 256, 0, stream>>>(Vtmp, Vn, Qh, Kh, q2a, aqa, k2a, cka);
  pack_v<<<512, 256, 0, stream>>>(Vtmp, Vn, VTb, l1a);
  attn<<<dim3(16, 32), 256, 0, stream>>>(Qh, Kh, VTb, q2a, aqa, k2a, cka, l1a, (float*)d_out);
}

// Round 4
// 182.681 us; speedup vs baseline: 2.1062x; 1.0454x over previous
//
#include <hip/hip_runtime.h>
#include <math.h>

#define EPSf 1e-7f
typedef unsigned short u16;
typedef __attribute__((ext_vector_type(8))) short bf16x8;
typedef __attribute__((ext_vector_type(4))) float f32x4;

__device__ __forceinline__ float bf2f(u16 u) {
  union { unsigned int i; float f; } x; x.i = ((unsigned int)u) << 16; return x.f;
}
__device__ __forceinline__ u16 f2bf(float f) {  // RNE
  union { float f; unsigned int i; } x; x.f = f;
  unsigned int r = x.i + 0x7fffu + ((x.i >> 16) & 1u);
  return (u16)(r >> 16);
}
__device__ __forceinline__ void gll16(const void* g, void* l) {
  __builtin_amdgcn_global_load_lds((__attribute__((address_space(1))) void*)(g),
                                   (__attribute__((address_space(3))) void*)(l),
                                   16, 0, 0);
}

// ---------------- split_x: x -> Xh/Xl bf16 planes + row norms Xn; zero Vn, Zn --------
// grid 6144 (2 rows per block over 3*4096 rows), block 256
__global__ __launch_bounds__(256) void split_x(
    const float* __restrict__ xq, const float* __restrict__ xk, const float* __restrict__ xv,
    u16* __restrict__ Xh, u16* __restrict__ Xl,
    float* __restrict__ Xn, float* __restrict__ Vn, float* __restrict__ Zn) {
  if (blockIdx.x == 0) {
    #pragma unroll
    for (int j = 0; j < 6; ++j) Zn[threadIdx.x + 256 * j] = 0.f;
  }
  const int gr = blockIdx.x * 2 + (threadIdx.x >> 7);
  const int mat = gr >> 12, row = gr & 4095;
  const float* X = (mat == 0) ? xq : (mat == 1) ? xk : xv;
  const int f4 = threadIdx.x & 127;
  float4 x = ((const float4*)(X + (size_t)row * 512))[f4];
  u16 h0 = f2bf(x.x), h1 = f2bf(x.y), h2 = f2bf(x.z), h3 = f2bf(x.w);
  u16 l0 = f2bf(x.x - bf2f(h0)), l1 = f2bf(x.y - bf2f(h1));
  u16 l2 = f2bf(x.z - bf2f(h2)), l3 = f2bf(x.w - bf2f(h3));
  ((ushort4*)(Xh + (size_t)gr * 512))[f4] = make_ushort4(h0, h1, h2, h3);
  ((ushort4*)(Xl + (size_t)gr * 512))[f4] = make_ushort4(l0, l1, l2, l3);
  float a = fmaf(x.x, x.x, fmaf(x.y, x.y, fmaf(x.z, x.z, x.w * x.w)));
  a += __shfl_xor(a, 1);  a += __shfl_xor(a, 2);  a += __shfl_xor(a, 4);
  a += __shfl_xor(a, 8);  a += __shfl_xor(a, 16); a += __shfl_xor(a, 32);
  __shared__ float red[4];
  if ((threadIdx.x & 63) == 0) red[threadIdx.x >> 6] = a;
  __syncthreads();
  if (threadIdx.x == 0)   { Xn[gr] = red[0] + red[1]; Vn[gr] = 0.f; }
  if (threadIdx.x == 128) { Xn[gr] = red[2] + red[3]; Vn[gr] = 0.f; }
}

// ---------------- split_z: z -> ZhT/ZlT (transposed bf16 hi/lo) + col norm partials ---
// grid 192 (3 mats x 8 col-groups x 8 k-tiles), block 256
__global__ __launch_bounds__(256) void split_z(
    const float* __restrict__ zq, const float* __restrict__ zk, const float* __restrict__ zv,
    u16* __restrict__ ZhT, u16* __restrict__ ZlT, float* __restrict__ Zn) {
  const int idx = blockIdx.x;
  const int mat = idx >> 6;
  const int cg = (idx >> 3) & 7, kt = idx & 7;
  const int c0 = cg * 64;
  const float* Z = (mat == 0) ? zq : (mat == 1) ? zk : zv;
  __shared__ float tile[64][68];
  const int t = threadIdx.x;
  {
    int kl = t >> 2;
    const float* src = Z + (size_t)(kt * 64 + kl) * 512 + c0 + (t & 3) * 16;
    #pragma unroll
    for (int j = 0; j < 4; ++j) {
      float4 v = *(const float4*)(src + 4 * j);
      *(float4*)&tile[kl][(t & 3) * 16 + 4 * j] = v;
    }
  }
  __syncthreads();
  const int cl = t >> 2, kg4 = t & 3;
  const size_t zo = (size_t)mat * 512 * 512;
  float csum = 0.f;
  #pragma unroll
  for (int jj = 0; jj < 4; ++jj) {
    u16 hb[4], lb[4];
    #pragma unroll
    for (int qq = 0; qq < 4; ++qq) {
      float zval = tile[kg4 * 16 + jj * 4 + qq][cl];
      csum = fmaf(zval, zval, csum);
      u16 hh = f2bf(zval);
      hb[qq] = hh;
      lb[qq] = f2bf(zval - bf2f(hh));
    }
    size_t o = zo + (size_t)(c0 + cl) * 512 + kt * 64 + kg4 * 16 + jj * 4;
    *(ushort4*)(ZhT + o) = make_ushort4(hb[0], hb[1], hb[2], hb[3]);
    *(ushort4*)(ZlT + o) = make_ushort4(lb[0], lb[1], lb[2], lb[3]);
  }
  csum += __shfl_xor(csum, 1);
  csum += __shfl_xor(csum, 2);
  if (kg4 == 0) atomicAdd(&Zn[mat * 512 + c0 + cl], csum);
}

// ---------------- proj_gemm: bf16x2-split MFMA GEMM + h_linear epilogue --------------
// 64x128 tile; grid (64,4,3) = 768 blocks (3/CU); WM column meta computed inline
__global__ __launch_bounds__(256) void proj_gemm(
    const u16* __restrict__ Xh, const u16* __restrict__ Xl,
    const u16* __restrict__ ZhT, const u16* __restrict__ ZlT,
    const float* __restrict__ Xn, const float* __restrict__ Zn,
    const float* __restrict__ rq, const float* __restrict__ rk, const float* __restrict__ rv,
    float* __restrict__ Vtmp, float* __restrict__ Vn) {
  const int m0 = blockIdx.x * 64;
  const int n0 = blockIdx.y * 128;
  const int mat = blockIdx.z;
  const size_t xoff = (size_t)mat * 4096 * 512;
  const size_t zoff = (size_t)mat * 512 * 512;
  const int t = threadIdx.x, wv = t >> 6, lane = t & 63;
  const int l15 = lane & 15, quad = lane >> 4;
  const int wm = wv >> 1, wn = wv & 1;

  // SM layout (u16): Ah @0 (64x32), Al @2048, Bh @4096 (128x32), Bl @8192
  __shared__ __align__(16) u16 SM[12288];
  __shared__ float lams[64], lam1s[64], wmxs[128], wmys[128], wmzs[128];

  if (t < 64) {
    float x2 = Xn[mat * 4096 + m0 + t];
    float lam = 2.f / fmaxf(1.f - x2, EPSf);
    lams[t] = lam; lam1s[t] = lam - 1.f;
  }
  if (t < 128) {
    float zn = fmaxf(sqrtf(Zn[mat * 512 + n0 + t]), EPSf);
    const float* R = (mat == 0) ? rq : (mat == 1) ? rk : rv;
    float tr = 2.f * R[n0 + t];
    float e = expf(tr), ei = 1.f / e;
    wmxs[t] = 0.5f * (e + ei) / zn;
    wmys[t] = 0.5f * (e - ei);
    wmzs[t] = 2.f * zn;
  }

  f32x4 acc[2][4];
  #pragma unroll
  for (int i = 0; i < 2; ++i)
    #pragma unroll
    for (int j = 0; j < 4; ++j) acc[i][j] = (f32x4){0.f, 0.f, 0.f, 0.f};

  // staging: 24 chunks of 16 rows x 32 u16 (1 KB = one gll16); wave w takes w, w+4, ...
  const u16* gs[6];
  u16* ld[6];
  #pragma unroll
  for (int ci = 0; ci < 6; ++ci) {
    int c = wv + 4 * ci;
    const u16* arr; int row0, lo;
    if (c < 4)       { arr = Xh + xoff;  row0 = m0 + 16 * c;        lo = c * 512; }
    else if (c < 8)  { arr = Xl + xoff;  row0 = m0 + 16 * (c - 4);  lo = 2048 + (c - 4) * 512; }
    else if (c < 16) { arr = ZhT + zoff; row0 = n0 + 16 * (c - 8);  lo = 4096 + (c - 8) * 512; }
    else             { arr = ZlT + zoff; row0 = n0 + 16 * (c - 16); lo = 8192 + (c - 16) * 512; }
    gs[ci] = arr + (size_t)(row0 + (lane >> 2)) * 512 + (lane & 3) * 8;
    ld[ci] = SM + lo;
  }

  for (int k0 = 0; k0 < 512; k0 += 32) {
    __syncthreads();
    #pragma unroll
    for (int ci = 0; ci < 6; ++ci) gll16(gs[ci] + k0, ld[ci]);
    __syncthreads();
    bf16x8 ah[2], al[2], bh_[4], bl_[4];
    #pragma unroll
    for (int i = 0; i < 2; ++i) {
      int ra = wm * 32 + i * 16 + l15;
      ah[i] = *(const bf16x8*)&SM[ra * 32 + quad * 8];
      al[i] = *(const bf16x8*)&SM[2048 + ra * 32 + quad * 8];
    }
    #pragma unroll
    for (int j = 0; j < 4; ++j) {
      int rb = wn * 64 + j * 16 + l15;
      bh_[j] = *(const bf16x8*)&SM[4096 + rb * 32 + quad * 8];
      bl_[j] = *(const bf16x8*)&SM[8192 + rb * 32 + quad * 8];
    }
    #pragma unroll
    for (int i = 0; i < 2; ++i)
      #pragma unroll
      for (int j = 0; j < 4; ++j) {
        acc[i][j] = __builtin_amdgcn_mfma_f32_16x16x32_bf16(ah[i], bh_[j], acc[i][j], 0, 0, 0);
        acc[i][j] = __builtin_amdgcn_mfma_f32_16x16x32_bf16(ah[i], bl_[j], acc[i][j], 0, 0, 0);
        acc[i][j] = __builtin_amdgcn_mfma_f32_16x16x32_bf16(al[i], bh_[j], acc[i][j], 0, 0, 0);
      }
  }

  // epilogue: v = 2*zn*asinh(lam*xz*cosh2r/zn - (lam-1)*sinh2r); row |v|^2 partials
  #pragma unroll
  for (int i = 0; i < 2; ++i) {
    float rsum[4] = {0.f, 0.f, 0.f, 0.f};
    #pragma unroll
    for (int j = 0; j < 4; ++j) {
      int nl = wn * 64 + j * 16 + l15;
      float wx = wmxs[nl], wy = wmys[nl], wz = wmzs[nl];
      #pragma unroll
      for (int r = 0; r < 4; ++r) {
        int ml = wm * 32 + i * 16 + quad * 4 + r;
        float tt = lams[ml] * acc[i][j][r] * wx - lam1s[ml] * wy;
        float v = wz * logf(tt + sqrtf(fmaf(tt, tt, 1.f)));
        Vtmp[xoff + (size_t)(m0 + ml) * 512 + (n0 + nl)] = v;
        rsum[r] = fmaf(v, v, rsum[r]);
      }
    }
    #pragma unroll
    for (int r = 0; r < 4; ++r) {
      rsum[r] += __shfl_xor(rsum[r], 1);
      rsum[r] += __shfl_xor(rsum[r], 2);
      rsum[r] += __shfl_xor(rsum[r], 4);
      rsum[r] += __shfl_xor(rsum[r], 8);
    }
    if (l15 == 0) {
      #pragma unroll
      for (int r = 0; r < 4; ++r)
        atomicAdd(&Vn[mat * 4096 + m0 + wm * 32 + i * 16 + quad * 4 + r], rsum[r]);
    }
  }
}

// ---------------- pack (merged): qk relayout+scalars, v transpose+lam-fold ----------
// grid 768: bx<256 -> qk path (2 mats x 128 row-blocks); bx>=256 -> v path (32bh x 16 st)
__global__ __launch_bounds__(256) void pack(
    const float* __restrict__ Vtmp, const float* __restrict__ Vn,
    u16* __restrict__ Qh, u16* __restrict__ Kh, u16* __restrict__ VTb,
    float* __restrict__ q2a, float* __restrict__ aqa, float4* __restrict__ ksc) {
  __shared__ u16 tile[64][72];
  __shared__ float lams[64];
  const int t = threadIdx.x;
  if (blockIdx.x < 256) {
    const int mat = blockIdx.x >> 7;       // 0=Q, 1=K
    const int rb = blockIdx.x & 127;
    const int r = t >> 3, h = t & 7;
    const int row = rb * 32 + r;
    const size_t gr = (size_t)mat * 4096 + row;
    const float sc = 1.f / (1.f + sqrtf(1.f + Vn[gr]));
    const float* src = Vtmp + gr * 512 + h * 64;
    const int b = row >> 10, s = row & 1023;
    u16* dst = (mat ? Kh : Qh) + ((size_t)(b * 8 + h) * 1024 + s) * 64;
    float nrm = 0.f;
    #pragma unroll
    for (int j = 0; j < 16; ++j) {
      float4 x = *(const float4*)(src + 4 * j);
      u16 u0 = f2bf(x.x * sc), u1 = f2bf(x.y * sc), u2 = f2bf(x.z * sc), u3 = f2bf(x.w * sc);
      *(ushort4*)(dst + 4 * j) = make_ushort4(u0, u1, u2, u3);
      float f0 = bf2f(u0), f1 = bf2f(u1), f2 = bf2f(u2), f3 = bf2f(u3);
      nrm += f0 * f0 + f1 * f1 + f2 * f2 + f3 * f3;
    }
    const size_t so = (size_t)(b * 8 + h) * 1024 + s;
    if (mat == 0) { q2a[so] = nrm; aqa[so] = 1.f / fmaxf(1.f - nrm, EPSf); }
    else {
      float2 kk = make_float2(nrm, 2.f / fmaxf(1.f - nrm, EPSf));
      *(float2*)&ksc[so] = kk;              // .x = k2, .y = ck
    }
  } else {
    const int idx = blockIdx.x - 256;
    const int bh = idx >> 4, st = idx & 15;
    const int b = bh >> 3, h = bh & 7;
    {
      const int s = t >> 2, dg = t & 3;
      const size_t gr = (size_t)2 * 4096 + b * 1024 + st * 64 + s;
      const float sc = 1.f / (1.f + sqrtf(1.f + Vn[gr]));
      const float* src = Vtmp + gr * 512 + h * 64 + dg * 16;
      float nrm = 0.f;
      #pragma unroll
      for (int j = 0; j < 4; ++j) {
        float4 x = *(const float4*)(src + 4 * j);
        u16 u0 = f2bf(x.x * sc), u1 = f2bf(x.y * sc), u2 = f2bf(x.z * sc), u3 = f2bf(x.w * sc);
        *(ushort4*)&tile[s][dg * 16 + 4 * j] = make_ushort4(u0, u1, u2, u3);
        float f0 = bf2f(u0), f1 = bf2f(u1), f2 = bf2f(u2), f3 = bf2f(u3);
        nrm += f0 * f0 + f1 * f1 + f2 * f2 + f3 * f3;
      }
      nrm += __shfl_xor(nrm, 1);
      nrm += __shfl_xor(nrm, 2);
      if (dg == 0) {
        float lam = 2.f / fmaxf(1.f - nrm, EPSf);
        lams[s] = lam;
        ((float*)&ksc[(size_t)bh * 1024 + st * 64 + s])[3] = lam - 1.f;  // .w = lam_v - 1
      }
    }
    __syncthreads();
    const int d = t >> 2, sg = t & 3;
    u16 ob[16];
    #pragma unroll
    for (int j = 0; j < 16; ++j) {
      int ss = sg * 16 + j;
      ob[j] = f2bf(bf2f(tile[ss][d]) * lams[ss]);
    }
    u16* dst = VTb + ((size_t)bh * 64 + d) * 1024 + st * 64 + sg * 16;
    #pragma unroll
    for (int j = 0; j < 4; ++j)
      *(ushort4*)(dst + 4 * j) = make_ushort4(ob[4 * j], ob[4 * j + 1], ob[4 * j + 2], ob[4 * j + 3]);
  }
}

// ---------------- attn: 32-query tiles, waves 2x2 over (q-half, k-half) -------------
// grid (32 q-tiles, 32 bh) = 1024 blocks (4/CU)
__global__ __launch_bounds__(256) void attn(
    const u16* __restrict__ Qh, const u16* __restrict__ Kh, const u16* __restrict__ VTb,
    const float* __restrict__ q2a, const float* __restrict__ aqa,
    const float4* __restrict__ ksc, float* __restrict__ out) {
  const int bh = blockIdx.y;
  const int b = bh >> 3, h = bh & 7;
  const int q0 = blockIdx.x * 32;
  const int t = threadIdx.x, wv = t >> 6, lane = t & 63;
  const int l15 = lane & 15, quad = lane >> 4;
  const int qh = wv >> 1, kh = wv & 1;

  __shared__ __align__(16) u16 Qs[32 * 72];
  __shared__ __align__(16) u16 Ks[64 * 72];
  __shared__ __align__(16) u16 VsT[64 * 72];
  __shared__ __align__(16) u16 Ws[4 * 16 * 36];
  __shared__ float dens[64];
  __shared__ __align__(16) float nums[2][16][68];

  // stage Q once (32 rows x 64 d)
  {
    int row = t >> 3, g = t & 7;
    float4 v = *(const float4*)(Qh + ((size_t)bh * 1024 + q0 + row) * 64 + g * 8);
    *(float4*)&Qs[row * 72 + g * 8] = v;
  }
  float q2r[4], aqr[4];
  #pragma unroll
  for (int r = 0; r < 4; ++r) {
    int qi = bh * 1024 + q0 + qh * 16 + quad * 4 + r;
    q2r[r] = q2a[qi];
    aqr[r] = aqa[qi];
  }
  __syncthreads();
  const bf16x8 qf0 = *(const bf16x8*)&Qs[(qh * 16 + l15) * 72 + quad * 8];
  const bf16x8 qf1 = *(const bf16x8*)&Qs[(qh * 16 + l15) * 72 + 32 + quad * 8];

  f32x4 num[4];
  #pragma unroll
  for (int i = 0; i < 4; ++i) num[i] = (f32x4){0.f, 0.f, 0.f, 0.f};
  float denp[4] = {0.f, 0.f, 0.f, 0.f};

  for (int kt = 0; kt < 16; ++kt) {
    __syncthreads();  // previous iteration done reading Ks/VsT
    {
      int row = t >> 3, g = t & 7;
      #pragma unroll
      for (int p = 0; p < 2; ++p) {
        int rr = row + 32 * p;
        float4 kv = *(const float4*)(Kh + ((size_t)bh * 1024 + kt * 64 + rr) * 64 + g * 8);
        *(float4*)&Ks[rr * 72 + g * 8] = kv;
        float4 vvv = *(const float4*)(VTb + ((size_t)bh * 64 + rr) * 1024 + kt * 64 + g * 8);
        *(float4*)&VsT[rr * 72 + g * 8] = vvv;
      }
    }
    __syncthreads();

    // phase A: scores for wave's 16 q x 32 k
    f32x4 s0 = (f32x4){0.f, 0.f, 0.f, 0.f};
    f32x4 s1 = (f32x4){0.f, 0.f, 0.f, 0.f};
    {
      const bf16x8 ka0 = *(const bf16x8*)&Ks[(kh * 32 + l15) * 72 + quad * 8];
      const bf16x8 ka1 = *(const bf16x8*)&Ks[(kh * 32 + l15) * 72 + 32 + quad * 8];
      const bf16x8 kb0 = *(const bf16x8*)&Ks[(kh * 32 + 16 + l15) * 72 + quad * 8];
      const bf16x8 kb1 = *(const bf16x8*)&Ks[(kh * 32 + 16 + l15) * 72 + 32 + quad * 8];
      s0 = __builtin_amdgcn_mfma_f32_16x16x32_bf16(qf0, ka0, s0, 0, 0, 0);
      s0 = __builtin_amdgcn_mfma_f32_16x16x32_bf16(qf1, ka1, s0, 0, 0, 0);
      s1 = __builtin_amdgcn_mfma_f32_16x16x32_bf16(qf0, kb0, s1, 0, 0, 0);
      s1 = __builtin_amdgcn_mfma_f32_16x16x32_bf16(qf1, kb1, s1, 0, 0, 0);
    }
    // weight chain: w = (1+u) - sqrt(u(u+2)); 8 scores/thread
    #pragma unroll
    for (int tn = 0; tn < 2; ++tn) {
      float4 kv = ksc[(size_t)bh * 1024 + kt * 64 + kh * 32 + tn * 16 + l15];
      float k2 = kv.x, ck = kv.y, l1f = kv.w;
      f32x4 s = tn ? s1 : s0;
      #pragma unroll
      for (int r = 0; r < 4; ++r) {
        float d2 = fmaxf(fmaf(-2.f, s[r], q2r[r] + k2), 0.f);
        float u = fmaxf(d2 * ck * aqr[r], EPSf);
        float w = (1.f + u) - sqrtf(u * (u + 2.f));
        u16 wb = f2bf(w);
        denp[r] = fmaf(bf2f(wb), l1f, denp[r]);
        Ws[wv * 576 + (quad * 4 + r) * 36 + tn * 16 + l15] = wb;
      }
    }
    // phase B: num += V^T(d x 32k) @ W^T(32k x 16q), wave-private Ws (no barrier)
    const bf16x8 wf = *(const bf16x8*)&Ws[wv * 576 + l15 * 36 + quad * 8];
    #pragma unroll
    for (int tm = 0; tm < 4; ++tm) {
      const bf16x8 vf = *(const bf16x8*)&VsT[(tm * 16 + l15) * 72 + kh * 32 + quad * 8];
      num[tm] = __builtin_amdgcn_mfma_f32_16x16x32_bf16(vf, wf, num[tm], 0, 0, 0);
    }
  }

  // cross-lane den reduce (over the 16 l15 lanes = 16 keys per tn, tn summed already)
  #pragma unroll
  for (int r = 0; r < 4; ++r) {
    denp[r] += __shfl_xor(denp[r], 1);
    denp[r] += __shfl_xor(denp[r], 2);
    denp[r] += __shfl_xor(denp[r], 4);
    denp[r] += __shfl_xor(denp[r], 8);
  }
  if (l15 == 0) {
    #pragma unroll
    for (int r = 0; r < 4; ++r) dens[wv * 16 + quad * 4 + r] = denp[r];
  }
  if (kh == 1) {
    #pragma unroll
    for (int tm = 0; tm < 4; ++tm)
      *(float4*)&nums[qh][l15][tm * 16 + quad * 4] =
          make_float4(num[tm][0], num[tm][1], num[tm][2], num[tm][3]);
  }
  __syncthreads();
  if (kh == 0) {
    #pragma unroll
    for (int tm = 0; tm < 4; ++tm) {
      float4 o = *(const float4*)&nums[qh][l15][tm * 16 + quad * 4];
      num[tm][0] += o.x; num[tm][1] += o.y; num[tm][2] += o.z; num[tm][3] += o.w;
    }
    float den = dens[qh * 32 + l15] + dens[qh * 32 + 16 + l15];
    den = (fabsf(den) < EPSf) ? EPSf : den;
    float inv = 1.f / den;
    float mv[4][4];
    float p = 0.f;
    #pragma unroll
    for (int tm = 0; tm < 4; ++tm)
      #pragma unroll
      for (int r = 0; r < 4; ++r) {
        float m = num[tm][r] * inv;
        mv[tm][r] = m;
        p = fmaf(m, m, p);
      }
    p += __shfl_xor(p, 16);
    p += __shfl_xor(p, 32);
    float mn = sqrtf(p);
    float mnc = fmaxf(mn, EPSf);
    float tt2 = fminf(mnc, 1.f - 1e-6f);
    float scale = tt2 / ((1.f + sqrtf(fmaxf(1.f - tt2 * tt2, 0.f))) * mnc);
    const size_t qg = (size_t)b * 1024 + q0 + qh * 16 + l15;
    #pragma unroll
    for (int tm = 0; tm < 4; ++tm) {
      float4 o = make_float4(mv[tm][0] * scale, mv[tm][1] * scale,
                             mv[tm][2] * scale, mv[tm][3] * scale);
      *(float4*)(out + qg * 512 + h * 64 + tm * 16 + quad * 4) = o;
    }
  }
}

// ---------------- host ----------------
extern "C" void kernel_launch(void* const* d_in, const int* in_sizes, int n_in,
                              void* d_out, int out_size, void* d_ws, size_t ws_size,
                              hipStream_t stream) {
  (void)in_sizes; (void)n_in; (void)out_size; (void)ws_size;
  const float* q  = (const float*)d_in[0];
  const float* k  = (const float*)d_in[1];
  const float* v  = (const float*)d_in[2];
  const float* zq = (const float*)d_in[3];
  const float* rq = (const float*)d_in[4];
  const float* zk = (const float*)d_in[5];
  const float* rk = (const float*)d_in[6];
  const float* zv = (const float*)d_in[7];
  const float* rv = (const float*)d_in[8];

  unsigned char* ws = (unsigned char*)d_ws;
  // phase-1 region:
  u16*   Xh   = (u16*)(ws + 0);          // 12582912
  u16*   Xl   = (u16*)(ws + 12582912);   // 12582912
  u16*   ZhT  = (u16*)(ws + 25165824);   // 1572864
  u16*   ZlT  = (u16*)(ws + 26738688);   // 1572864
  float* Vtmp = (float*)(ws + 28311552); // 25165824
  float* Xn   = (float*)(ws + 53477376); // 49152
  float* Vn   = (float*)(ws + 53526528); // 49152
  float* Zn   = (float*)(ws + 53575680); // 6144   -> end 53581824 (~53.6 MB)
  // phase-2 packed arrays overlay the dead Xh/Xl region (proj_gemm done):
  u16*   Qh   = (u16*)(ws + 0);          // 4194304
  u16*   Kh   = (u16*)(ws + 4194304);    // 4194304
  u16*   VTb  = (u16*)(ws + 8388608);    // 4194304
  float* q2a  = (float*)(ws + 12582912); // 131072
  float* aqa  = (float*)(ws + 12713984); // 131072
  float4* ksc = (float4*)(ws + 12845056);// 524288 -> 13369344 (< 25165824 OK)

  split_x<<<6144, 256, 0, stream>>>(q, k, v, Xh, Xl, Xn, Vn, Zn);
  split_z<<<192, 256, 0, stream>>>(zq, zk, zv, ZhT, ZlT, Zn);
  proj_gemm<<<dim3(64, 4, 3), 256, 0, stream>>>(Xh, Xl, ZhT, ZlT, Xn, Zn, rq, rk, rv, Vtmp, Vn);
  pack<<<768, 256, 0, stream>>>(Vtmp, Vn, Qh, Kh, VTb, q2a, aqa, ksc);
  attn<<<dim3(32, 32), 256, 0, stream>>>(Qh, Kh, VTb, q2a, aqa, ksc, (float*)d_out);
}

// Round 6
// 177.295 us; speedup vs baseline: 2.1702x; 1.0304x over previous
//
#include <hip/hip_runtime.h>
#include <hip/hip_bf16.h>
#include <math.h>

#define EPSf 1e-7f
typedef unsigned short u16;
typedef __attribute__((ext_vector_type(8))) short bf16x8;
typedef __attribute__((ext_vector_type(4))) float f32x4;

__device__ __forceinline__ float bf2f(u16 u) {
  union { unsigned int i; float f; } x; x.i = ((unsigned int)u) << 16; return x.f;
}
__device__ __forceinline__ u16 f2bf(float f) {  // RNE
  union { float f; unsigned int i; } x; x.f = f;
  unsigned int r = x.i + 0x7fffu + ((x.i >> 16) & 1u);
  return (u16)(r >> 16);
}
__device__ __forceinline__ void gll16(const void* g, void* l) {
  __builtin_amdgcn_global_load_lds((__attribute__((address_space(1))) void*)(g),
                                   (__attribute__((address_space(3))) void*)(l),
                                   16, 0, 0);
}

// ---------------- split_x: x -> Xh/Xl bf16 planes + row norms Xn; zero Vn, Zn --------
__global__ __launch_bounds__(256) void split_x(
    const float* __restrict__ xq, const float* __restrict__ xk, const float* __restrict__ xv,
    u16* __restrict__ Xh, u16* __restrict__ Xl,
    float* __restrict__ Xn, float* __restrict__ Vn, float* __restrict__ Zn) {
  if (blockIdx.x == 0) {
    #pragma unroll
    for (int j = 0; j < 6; ++j) Zn[threadIdx.x + 256 * j] = 0.f;
  }
  const int gr = blockIdx.x * 2 + (threadIdx.x >> 7);
  const int mat = gr >> 12, row = gr & 4095;
  const float* X = (mat == 0) ? xq : (mat == 1) ? xk : xv;
  const int f4 = threadIdx.x & 127;
  float4 x = ((const float4*)(X + (size_t)row * 512))[f4];
  u16 h0 = f2bf(x.x), h1 = f2bf(x.y), h2 = f2bf(x.z), h3 = f2bf(x.w);
  u16 l0 = f2bf(x.x - bf2f(h0)), l1 = f2bf(x.y - bf2f(h1));
  u16 l2 = f2bf(x.z - bf2f(h2)), l3 = f2bf(x.w - bf2f(h3));
  ((ushort4*)(Xh + (size_t)gr * 512))[f4] = make_ushort4(h0, h1, h2, h3);
  ((ushort4*)(Xl + (size_t)gr * 512))[f4] = make_ushort4(l0, l1, l2, l3);
  float a = fmaf(x.x, x.x, fmaf(x.y, x.y, fmaf(x.z, x.z, x.w * x.w)));
  a += __shfl_xor(a, 1);  a += __shfl_xor(a, 2);  a += __shfl_xor(a, 4);
  a += __shfl_xor(a, 8);  a += __shfl_xor(a, 16); a += __shfl_xor(a, 32);
  __shared__ float red[4];
  if ((threadIdx.x & 63) == 0) red[threadIdx.x >> 6] = a;
  __syncthreads();
  if (threadIdx.x == 0)   { Xn[gr] = red[0] + red[1]; Vn[gr] = 0.f; }
  if (threadIdx.x == 128) { Xn[gr] = red[2] + red[3]; Vn[gr] = 0.f; }
}

// ---------------- split_z: z -> ZhT/ZlT (transposed bf16 hi/lo) + col norm partials ---
__global__ __launch_bounds__(256) void split_z(
    const float* __restrict__ zq, const float* __restrict__ zk, const float* __restrict__ zv,
    u16* __restrict__ ZhT, u16* __restrict__ ZlT, float* __restrict__ Zn) {
  const int idx = blockIdx.x;
  const int mat = idx >> 6;
  const int cg = (idx >> 3) & 7, kt = idx & 7;
  const int c0 = cg * 64;
  const float* Z = (mat == 0) ? zq : (mat == 1) ? zk : zv;
  __shared__ float tile[64][68];
  const int t = threadIdx.x;
  {
    int kl = t >> 2;
    const float* src = Z + (size_t)(kt * 64 + kl) * 512 + c0 + (t & 3) * 16;
    #pragma unroll
    for (int j = 0; j < 4; ++j) {
      float4 v = *(const float4*)(src + 4 * j);
      *(float4*)&tile[kl][(t & 3) * 16 + 4 * j] = v;
    }
  }
  __syncthreads();
  const int cl = t >> 2, kg4 = t & 3;
  const size_t zo = (size_t)mat * 512 * 512;
  float csum = 0.f;
  #pragma unroll
  for (int jj = 0; jj < 4; ++jj) {
    u16 hb[4], lb[4];
    #pragma unroll
    for (int qq = 0; qq < 4; ++qq) {
      float zval = tile[kg4 * 16 + jj * 4 + qq][cl];
      csum = fmaf(zval, zval, csum);
      u16 hh = f2bf(zval);
      hb[qq] = hh;
      lb[qq] = f2bf(zval - bf2f(hh));
    }
    size_t o = zo + (size_t)(c0 + cl) * 512 + kt * 64 + kg4 * 16 + jj * 4;
    *(ushort4*)(ZhT + o) = make_ushort4(hb[0], hb[1], hb[2], hb[3]);
    *(ushort4*)(ZlT + o) = make_ushort4(lb[0], lb[1], lb[2], lb[3]);
  }
  csum += __shfl_xor(csum, 1);
  csum += __shfl_xor(csum, 2);
  if (kg4 == 0) atomicAdd(&Zn[mat * 512 + c0 + cl], csum);
}

// ---------------- proj_gemm: bf16x2-split MFMA GEMM + h_linear epilogue --------------
__global__ __launch_bounds__(256) void proj_gemm(
    const u16* __restrict__ Xh, const u16* __restrict__ Xl,
    const u16* __restrict__ ZhT, const u16* __restrict__ ZlT,
    const float* __restrict__ Xn, const float* __restrict__ Zn,
    const float* __restrict__ rq, const float* __restrict__ rk, const float* __restrict__ rv,
    float* __restrict__ Vtmp, float* __restrict__ Vn) {
  const int m0 = blockIdx.x * 64;
  const int n0 = blockIdx.y * 128;
  const int mat = blockIdx.z;
  const size_t xoff = (size_t)mat * 4096 * 512;
  const size_t zoff = (size_t)mat * 512 * 512;
  const int t = threadIdx.x, wv = t >> 6, lane = t & 63;
  const int l15 = lane & 15, quad = lane >> 4;
  const int wm = wv >> 1, wn = wv & 1;

  __shared__ __align__(16) u16 SM[12288];
  __shared__ float lams[64], lam1s[64], wmxs[128], wmys[128], wmzs[128];

  if (t < 64) {
    float x2 = Xn[mat * 4096 + m0 + t];
    float lam = 2.f / fmaxf(1.f - x2, EPSf);
    lams[t] = lam; lam1s[t] = lam - 1.f;
  }
  if (t < 128) {
    float zn = fmaxf(sqrtf(Zn[mat * 512 + n0 + t]), EPSf);
    const float* R = (mat == 0) ? rq : (mat == 1) ? rk : rv;
    float tr = 2.f * R[n0 + t];
    float e = expf(tr), ei = 1.f / e;
    wmxs[t] = 0.5f * (e + ei) / zn;
    wmys[t] = 0.5f * (e - ei);
    wmzs[t] = 2.f * zn;
  }

  f32x4 acc[2][4];
  #pragma unroll
  for (int i = 0; i < 2; ++i)
    #pragma unroll
    for (int j = 0; j < 4; ++j) acc[i][j] = (f32x4){0.f, 0.f, 0.f, 0.f};

  const u16* gs[6];
  u16* ld[6];
  #pragma unroll
  for (int ci = 0; ci < 6; ++ci) {
    int c = wv + 4 * ci;
    const u16* arr; int row0, lo;
    if (c < 4)       { arr = Xh + xoff;  row0 = m0 + 16 * c;        lo = c * 512; }
    else if (c < 8)  { arr = Xl + xoff;  row0 = m0 + 16 * (c - 4);  lo = 2048 + (c - 4) * 512; }
    else if (c < 16) { arr = ZhT + zoff; row0 = n0 + 16 * (c - 8);  lo = 4096 + (c - 8) * 512; }
    else             { arr = ZlT + zoff; row0 = n0 + 16 * (c - 16); lo = 8192 + (c - 16) * 512; }
    gs[ci] = arr + (size_t)(row0 + (lane >> 2)) * 512 + (lane & 3) * 8;
    ld[ci] = SM + lo;
  }

  for (int k0 = 0; k0 < 512; k0 += 32) {
    __syncthreads();
    #pragma unroll
    for (int ci = 0; ci < 6; ++ci) gll16(gs[ci] + k0, ld[ci]);
    __syncthreads();
    bf16x8 ah[2], al[2], bh_[4], bl_[4];
    #pragma unroll
    for (int i = 0; i < 2; ++i) {
      int ra = wm * 32 + i * 16 + l15;
      ah[i] = *(const bf16x8*)&SM[ra * 32 + quad * 8];
      al[i] = *(const bf16x8*)&SM[2048 + ra * 32 + quad * 8];
    }
    #pragma unroll
    for (int j = 0; j < 4; ++j) {
      int rb = wn * 64 + j * 16 + l15;
      bh_[j] = *(const bf16x8*)&SM[4096 + rb * 32 + quad * 8];
      bl_[j] = *(const bf16x8*)&SM[8192 + rb * 32 + quad * 8];
    }
    #pragma unroll
    for (int i = 0; i < 2; ++i)
      #pragma unroll
      for (int j = 0; j < 4; ++j) {
        acc[i][j] = __builtin_amdgcn_mfma_f32_16x16x32_bf16(ah[i], bh_[j], acc[i][j], 0, 0, 0);
        acc[i][j] = __builtin_amdgcn_mfma_f32_16x16x32_bf16(ah[i], bl_[j], acc[i][j], 0, 0, 0);
        acc[i][j] = __builtin_amdgcn_mfma_f32_16x16x32_bf16(al[i], bh_[j], acc[i][j], 0, 0, 0);
      }
  }

  #pragma unroll
  for (int i = 0; i < 2; ++i) {
    float rsum[4] = {0.f, 0.f, 0.f, 0.f};
    #pragma unroll
    for (int j = 0; j < 4; ++j) {
      int nl = wn * 64 + j * 16 + l15;
      float wx = wmxs[nl], wy = wmys[nl], wz = wmzs[nl];
      #pragma unroll
      for (int r = 0; r < 4; ++r) {
        int ml = wm * 32 + i * 16 + quad * 4 + r;
        float tt = lams[ml] * acc[i][j][r] * wx - lam1s[ml] * wy;
        float v = wz * logf(tt + sqrtf(fmaf(tt, tt, 1.f)));
        Vtmp[xoff + (size_t)(m0 + ml) * 512 + (n0 + nl)] = v;
        rsum[r] = fmaf(v, v, rsum[r]);
      }
    }
    #pragma unroll
    for (int r = 0; r < 4; ++r) {
      rsum[r] += __shfl_xor(rsum[r], 1);
      rsum[r] += __shfl_xor(rsum[r], 2);
      rsum[r] += __shfl_xor(rsum[r], 4);
      rsum[r] += __shfl_xor(rsum[r], 8);
    }
    if (l15 == 0) {
      #pragma unroll
      for (int r = 0; r < 4; ++r)
        atomicAdd(&Vn[mat * 4096 + m0 + wm * 32 + i * 16 + quad * 4 + r], rsum[r]);
    }
  }
}

// ---------------- pack (merged): qk relayout+scalars, v transpose+lam-fold ----------
__global__ __launch_bounds__(256) void pack(
    const float* __restrict__ Vtmp, const float* __restrict__ Vn,
    u16* __restrict__ Qh, u16* __restrict__ Kh, u16* __restrict__ VTb,
    float* __restrict__ q2a, float* __restrict__ aqa, float4* __restrict__ ksc) {
  __shared__ u16 tile[64][72];
  __shared__ float lams[64];
  const int t = threadIdx.x;
  if (blockIdx.x < 256) {
    const int mat = blockIdx.x >> 7;       // 0=Q, 1=K
    const int rb = blockIdx.x & 127;
    const int r = t >> 3, h = t & 7;
    const int row = rb * 32 + r;
    const size_t gr = (size_t)mat * 4096 + row;
    const float sc = 1.f / (1.f + sqrtf(1.f + Vn[gr]));
    const float* src = Vtmp + gr * 512 + h * 64;
    const int b = row >> 10, s = row & 1023;
    u16* dst = (mat ? Kh : Qh) + ((size_t)(b * 8 + h) * 1024 + s) * 64;
    float nrm = 0.f;
    #pragma unroll
    for (int j = 0; j < 16; ++j) {
      float4 x = *(const float4*)(src + 4 * j);
      u16 u0 = f2bf(x.x * sc), u1 = f2bf(x.y * sc), u2 = f2bf(x.z * sc), u3 = f2bf(x.w * sc);
      *(ushort4*)(dst + 4 * j) = make_ushort4(u0, u1, u2, u3);
      float f0 = bf2f(u0), f1 = bf2f(u1), f2 = bf2f(u2), f3 = bf2f(u3);
      nrm += f0 * f0 + f1 * f1 + f2 * f2 + f3 * f3;
    }
    const size_t so = (size_t)(b * 8 + h) * 1024 + s;
    if (mat == 0) { q2a[so] = nrm; aqa[so] = 1.f / fmaxf(1.f - nrm, EPSf); }
    else {
      float2 kk = make_float2(nrm, 2.f / fmaxf(1.f - nrm, EPSf));
      *(float2*)&ksc[so] = kk;              // .x = k2, .y = ck
    }
  } else {
    const int idx = blockIdx.x - 256;
    const int bh = idx >> 4, st = idx & 15;
    const int b = bh >> 3, h = bh & 7;
    {
      const int s = t >> 2, dg = t & 3;
      const size_t gr = (size_t)2 * 4096 + b * 1024 + st * 64 + s;
      const float sc = 1.f / (1.f + sqrtf(1.f + Vn[gr]));
      const float* src = Vtmp + gr * 512 + h * 64 + dg * 16;
      float nrm = 0.f;
      #pragma unroll
      for (int j = 0; j < 4; ++j) {
        float4 x = *(const float4*)(src + 4 * j);
        u16 u0 = f2bf(x.x * sc), u1 = f2bf(x.y * sc), u2 = f2bf(x.z * sc), u3 = f2bf(x.w * sc);
        *(ushort4*)&tile[s][dg * 16 + 4 * j] = make_ushort4(u0, u1, u2, u3);
        float f0 = bf2f(u0), f1 = bf2f(u1), f2 = bf2f(u2), f3 = bf2f(u3);
        nrm += f0 * f0 + f1 * f1 + f2 * f2 + f3 * f3;
      }
      nrm += __shfl_xor(nrm, 1);
      nrm += __shfl_xor(nrm, 2);
      if (dg == 0) {
        float lam = 2.f / fmaxf(1.f - nrm, EPSf);
        lams[s] = lam;
        ((float*)&ksc[(size_t)bh * 1024 + st * 64 + s])[3] = lam - 1.f;  // .w = lam_v - 1
      }
    }
    __syncthreads();
    const int d = t >> 2, sg = t & 3;
    u16 ob[16];
    #pragma unroll
    for (int j = 0; j < 16; ++j) {
      int ss = sg * 16 + j;
      ob[j] = f2bf(bf2f(tile[ss][d]) * lams[ss]);
    }
    u16* dst = VTb + ((size_t)bh * 64 + d) * 1024 + st * 64 + sg * 16;
    #pragma unroll
    for (int j = 0; j < 4; ++j)
      *(ushort4*)(dst + 4 * j) = make_ushort4(ob[4 * j], ob[4 * j + 1], ob[4 * j + 2], ob[4 * j + 3]);
  }
}

// ---------------- attn: barrier-light, K/V direct from global, waves = 2q x 2kt ------
// grid (32 bh, 16 q-tiles of 64), block 256. bh fast dim -> same-head L2/XCD locality.
__global__ __launch_bounds__(256, 2) void attn(
    const u16* __restrict__ Qh, const u16* __restrict__ Kh, const u16* __restrict__ VTb,
    const float* __restrict__ q2a, const float* __restrict__ aqa,
    const float4* __restrict__ ksc, float* __restrict__ out) {
  const int bh = blockIdx.x;
  const int b = bh >> 3, h = bh & 7;
  const int q0 = blockIdx.y * 64;
  const int t = threadIdx.x, wv = t >> 6, lane = t & 63;
  const int l15 = lane & 15, quad = lane >> 4;
  const int qh = wv & 1, kh = wv >> 1;   // q-half, kt-parity

  __shared__ __align__(16) u16 Ws[4][32 * 72];      // per-wave W[q][k], stride 72 (64k + pad)
  __shared__ float k2s[4][64], cks[4][64], l1s[4][64];  // per-wave k scalars
  __shared__ __align__(16) float nums[2][32][68];   // kh=1 partials for combine
  __shared__ float dens[2][32];

  const size_t qkoff = (size_t)bh * 65536;

  // Q fragments (B-operand) + per-q scalars, loop-invariant
  bf16x8 qf[2][2];
  float q2r[2], aqr[2];
  #pragma unroll
  for (int qs = 0; qs < 2; ++qs) {
    int qrow = q0 + qh * 32 + qs * 16 + l15;
    const u16* qp = Qh + qkoff + (size_t)qrow * 64 + quad * 8;
    qf[qs][0] = *(const bf16x8*)qp;
    qf[qs][1] = *(const bf16x8*)(qp + 32);
    q2r[qs] = q2a[bh * 1024 + qrow];
    aqr[qs] = aqa[bh * 1024 + qrow];
  }

  f32x4 num[2][4];
  #pragma unroll
  for (int qs = 0; qs < 2; ++qs)
    #pragma unroll
    for (int tm = 0; tm < 4; ++tm) num[qs][tm] = (f32x4){0.f, 0.f, 0.f, 0.f};
  float denp[2] = {0.f, 0.f};

  // preload kt = kh
  bf16x8 kcur[8];
  #pragma unroll
  for (int tn = 0; tn < 4; ++tn)
    #pragma unroll
    for (int ks = 0; ks < 2; ++ks)
      kcur[tn * 2 + ks] = *(const bf16x8*)(Kh + qkoff +
          (size_t)(kh * 64 + tn * 16 + l15) * 64 + ks * 32 + quad * 8);
  float4 scur = ksc[bh * 1024 + kh * 64 + lane];

  #pragma unroll 2
  for (int i = 0; i < 8; ++i) {
    const int ktc = kh + 2 * i;
    const int kti = (i < 7) ? ktc + 2 : ktc;
    // prefetch next K tile + scalars (one kt ahead)
    bf16x8 knxt[8];
    #pragma unroll
    for (int tn = 0; tn < 4; ++tn)
      #pragma unroll
      for (int ks = 0; ks < 2; ++ks)
        knxt[tn * 2 + ks] = *(const bf16x8*)(Kh + qkoff +
            (size_t)(kti * 64 + tn * 16 + l15) * 64 + ks * 32 + quad * 8);
    float4 snxt = ksc[bh * 1024 + kti * 64 + lane];
    // V fragments for current kt (used in phase B, latency hidden by A+chain)
    bf16x8 vf[8];
    #pragma unroll
    for (int tm = 0; tm < 4; ++tm)
      #pragma unroll
      for (int ks = 0; ks < 2; ++ks)
        vf[tm * 2 + ks] = *(const bf16x8*)(VTb + qkoff +
            (size_t)(tm * 16 + l15) * 1024 + ktc * 64 + ks * 32 + quad * 8);
    // wave-private k scalars into LDS (in-wave order, no barrier)
    k2s[wv][lane] = scur.x;
    cks[wv][lane] = scur.y;
    l1s[wv][lane] = scur.w;

    // phase A + weight chain, per k-subtile
    #pragma unroll
    for (int tn = 0; tn < 4; ++tn) {
      const float4 k2v = *(const float4*)&k2s[wv][tn * 16 + quad * 4];
      const float4 ckv = *(const float4*)&cks[wv][tn * 16 + quad * 4];
      const float4 l1v = *(const float4*)&l1s[wv][tn * 16 + quad * 4];
      #pragma unroll
      for (int qs = 0; qs < 2; ++qs) {
        f32x4 s = (f32x4){0.f, 0.f, 0.f, 0.f};
        s = __builtin_amdgcn_mfma_f32_16x16x32_bf16(kcur[tn * 2 + 0], qf[qs][0], s, 0, 0, 0);
        s = __builtin_amdgcn_mfma_f32_16x16x32_bf16(kcur[tn * 2 + 1], qf[qs][1], s, 0, 0, 0);
        unsigned up[2];
        #pragma unroll
        for (int pr = 0; pr < 2; ++pr) {
          float w2[2];
          #pragma unroll
          for (int e = 0; e < 2; ++e) {
            const int r = pr * 2 + e;
            float d2 = fmaxf(fmaf(-2.f, s[r], q2r[qs] + ((const float*)&k2v)[r]), 0.f);
            float u = fmaxf(d2 * ((const float*)&ckv)[r] * aqr[qs], EPSf);
            w2[e] = (1.f + u) - sqrtf(fmaf(u, u, u + u));
          }
          union { __hip_bfloat162 h2; unsigned u; } cv;
          cv.h2 = __float22bfloat162_rn(make_float2(w2[0], w2[1]));
          up[pr] = cv.u;
          float wlo = __uint_as_float(cv.u << 16);
          float whi = __uint_as_float(cv.u & 0xffff0000u);
          denp[qs] = fmaf(wlo, ((const float*)&l1v)[pr * 2 + 0], denp[qs]);
          denp[qs] = fmaf(whi, ((const float*)&l1v)[pr * 2 + 1], denp[qs]);
        }
        *(uint2*)&Ws[wv][(qs * 16 + l15) * 72 + tn * 16 + quad * 4] = make_uint2(up[0], up[1]);
      }
    }
    // phase B: num[d][q] += V^T W^T
    #pragma unroll
    for (int qs = 0; qs < 2; ++qs)
      #pragma unroll
      for (int ks = 0; ks < 2; ++ks) {
        const bf16x8 wf = *(const bf16x8*)&Ws[wv][(qs * 16 + l15) * 72 + ks * 32 + quad * 8];
        #pragma unroll
        for (int tm = 0; tm < 4; ++tm)
          num[qs][tm] = __builtin_amdgcn_mfma_f32_16x16x32_bf16(vf[tm * 2 + ks], wf, num[qs][tm], 0, 0, 0);
      }
    // rotate prefetch
    #pragma unroll
    for (int j = 0; j < 8; ++j) kcur[j] = knxt[j];
    scur = snxt;
  }

  // quad-reduce den partials
  #pragma unroll
  for (int qs = 0; qs < 2; ++qs) {
    denp[qs] += __shfl_xor(denp[qs], 16);
    denp[qs] += __shfl_xor(denp[qs], 32);
  }
  // 2-way kt combine through LDS
  if (kh == 1) {
    #pragma unroll
    for (int qs = 0; qs < 2; ++qs) {
      #pragma unroll
      for (int tm = 0; tm < 4; ++tm)
        *(float4*)&nums[qh][qs * 16 + l15][tm * 16 + quad * 4] =
            make_float4(num[qs][tm][0], num[qs][tm][1], num[qs][tm][2], num[qs][tm][3]);
      if (quad == 0) dens[qh][qs * 16 + l15] = denp[qs];
    }
  }
  __syncthreads();
  if (kh == 0) {
    #pragma unroll
    for (int qs = 0; qs < 2; ++qs) {
      float den = denp[qs] + dens[qh][qs * 16 + l15];
      den = (fabsf(den) < EPSf) ? EPSf : den;
      float inv = 1.f / den;
      float mv[4][4];
      float p = 0.f;
      #pragma unroll
      for (int tm = 0; tm < 4; ++tm) {
        float4 o = *(const float4*)&nums[qh][qs * 16 + l15][tm * 16 + quad * 4];
        mv[tm][0] = (num[qs][tm][0] + o.x) * inv;
        mv[tm][1] = (num[qs][tm][1] + o.y) * inv;
        mv[tm][2] = (num[qs][tm][2] + o.z) * inv;
        mv[tm][3] = (num[qs][tm][3] + o.w) * inv;
        p = fmaf(mv[tm][0], mv[tm][0], p); p = fmaf(mv[tm][1], mv[tm][1], p);
        p = fmaf(mv[tm][2], mv[tm][2], p); p = fmaf(mv[tm][3], mv[tm][3], p);
      }
      p += __shfl_xor(p, 16);
      p += __shfl_xor(p, 32);
      float mn = sqrtf(p);
      float mnc = fmaxf(mn, EPSf);
      float tt2 = fminf(mnc, 1.f - 1e-6f);
      float scale = tt2 / ((1.f + sqrtf(fmaxf(1.f - tt2 * tt2, 0.f))) * mnc);
      const size_t qg = (size_t)b * 1024 + q0 + qh * 32 + qs * 16 + l15;
      #pragma unroll
      for (int tm = 0; tm < 4; ++tm) {
        float4 o = make_float4(mv[tm][0] * scale, mv[tm][1] * scale,
                               mv[tm][2] * scale, mv[tm][3] * scale);
        *(float4*)(out + qg * 512 + h * 64 + tm * 16 + quad * 4) = o;
      }
    }
  }
}

// ---------------- host ----------------
extern "C" void kernel_launch(void* const* d_in, const int* in_sizes, int n_in,
                              void* d_out, int out_size, void* d_ws, size_t ws_size,
                              hipStream_t stream) {
  (void)in_sizes; (void)n_in; (void)out_size; (void)ws_size;
  const float* q  = (const float*)d_in[0];
  const float* k  = (const float*)d_in[1];
  const float* v  = (const float*)d_in[2];
  const float* zq = (const float*)d_in[3];
  const float* rq = (const float*)d_in[4];
  const float* zk = (const float*)d_in[5];
  const float* rk = (const float*)d_in[6];
  const float* zv = (const float*)d_in[7];
  const float* rv = (const float*)d_in[8];

  unsigned char* ws = (unsigned char*)d_ws;
  // phase-1 region:
  u16*   Xh   = (u16*)(ws + 0);          // 12582912
  u16*   Xl   = (u16*)(ws + 12582912);   // 12582912
  u16*   ZhT  = (u16*)(ws + 25165824);   // 1572864
  u16*   ZlT  = (u16*)(ws + 26738688);   // 1572864
  float* Vtmp = (float*)(ws + 28311552); // 25165824
  float* Xn   = (float*)(ws + 53477376); // 49152
  float* Vn   = (float*)(ws + 53526528); // 49152
  float* Zn   = (float*)(ws + 53575680); // 6144
  // phase-2 packed arrays overlay the dead Xh/Xl region (proj_gemm done):
  u16*   Qh   = (u16*)(ws + 0);          // 4194304
  u16*   Kh   = (u16*)(ws + 4194304);    // 4194304
  u16*   VTb  = (u16*)(ws + 8388608);    // 4194304
  float* q2a  = (float*)(ws + 12582912); // 131072
  float* aqa  = (float*)(ws + 12713984); // 131072
  float4* ksc = (float4*)(ws + 12845056);// 524288

  split_x<<<6144, 256, 0, stream>>>(q, k, v, Xh, Xl, Xn, Vn, Zn);
  split_z<<<192, 256, 0, stream>>>(zq, zk, zv, ZhT, ZlT, Zn);
  proj_gemm<<<dim3(64, 4, 3), 256, 0, stream>>>(Xh, Xl, ZhT, ZlT, Xn, Zn, rq, rk, rv, Vtmp, Vn);
  pack<<<768, 256, 0, stream>>>(Vtmp, Vn, Qh, Kh, VTb, q2a, aqa, ksc);
  attn<<<dim3(32, 16), 256, 0, stream>>>(Qh, Kh, VTb, q2a, aqa, ksc, (float*)d_out);
}

// Round 7
// 174.041 us; speedup vs baseline: 2.2108x; 1.0187x over previous
//
#include <hip/hip_runtime.h>
#include <hip/hip_bf16.h>
#include <math.h>

#define EPSf 1e-7f
typedef unsigned short u16;
typedef __attribute__((ext_vector_type(8))) short bf16x8;
typedef __attribute__((ext_vector_type(4))) float f32x4;

__device__ __forceinline__ float bf2f(u16 u) {
  union { unsigned int i; float f; } x; x.i = ((unsigned int)u) << 16; return x.f;
}
__device__ __forceinline__ u16 f2bf(float f) {  // RNE
  union { float f; unsigned int i; } x; x.f = f;
  unsigned int r = x.i + 0x7fffu + ((x.i >> 16) & 1u);
  return (u16)(r >> 16);
}
__device__ __forceinline__ void gll16(const void* g, void* l) {
  __builtin_amdgcn_global_load_lds((__attribute__((address_space(1))) void*)(g),
                                   (__attribute__((address_space(3))) void*)(l),
                                   16, 0, 0);
}

// ---------------- split_x: x -> Xh/Xl bf16 planes + row norms Xn; zero Vn, Zn --------
__global__ __launch_bounds__(256) void split_x(
    const float* __restrict__ xq, const float* __restrict__ xk, const float* __restrict__ xv,
    u16* __restrict__ Xh, u16* __restrict__ Xl,
    float* __restrict__ Xn, float* __restrict__ Vn, float* __restrict__ Zn) {
  if (blockIdx.x == 0) {
    #pragma unroll
    for (int j = 0; j < 6; ++j) Zn[threadIdx.x + 256 * j] = 0.f;
  }
  const int gr = blockIdx.x * 2 + (threadIdx.x >> 7);
  const int mat = gr >> 12, row = gr & 4095;
  const float* X = (mat == 0) ? xq : (mat == 1) ? xk : xv;
  const int f4 = threadIdx.x & 127;
  float4 x = ((const float4*)(X + (size_t)row * 512))[f4];
  u16 h0 = f2bf(x.x), h1 = f2bf(x.y), h2 = f2bf(x.z), h3 = f2bf(x.w);
  u16 l0 = f2bf(x.x - bf2f(h0)), l1 = f2bf(x.y - bf2f(h1));
  u16 l2 = f2bf(x.z - bf2f(h2)), l3 = f2bf(x.w - bf2f(h3));
  ((ushort4*)(Xh + (size_t)gr * 512))[f4] = make_ushort4(h0, h1, h2, h3);
  ((ushort4*)(Xl + (size_t)gr * 512))[f4] = make_ushort4(l0, l1, l2, l3);
  float a = fmaf(x.x, x.x, fmaf(x.y, x.y, fmaf(x.z, x.z, x.w * x.w)));
  a += __shfl_xor(a, 1);  a += __shfl_xor(a, 2);  a += __shfl_xor(a, 4);
  a += __shfl_xor(a, 8);  a += __shfl_xor(a, 16); a += __shfl_xor(a, 32);
  __shared__ float red[4];
  if ((threadIdx.x & 63) == 0) red[threadIdx.x >> 6] = a;
  __syncthreads();
  if (threadIdx.x == 0)   { Xn[gr] = red[0] + red[1]; Vn[gr] = 0.f; }
  if (threadIdx.x == 128) { Xn[gr] = red[2] + red[3]; Vn[gr] = 0.f; }
}

// ---------------- split_z: z -> ZhT/ZlT (transposed bf16 hi/lo) + col norm partials ---
__global__ __launch_bounds__(256) void split_z(
    const float* __restrict__ zq, const float* __restrict__ zk, const float* __restrict__ zv,
    u16* __restrict__ ZhT, u16* __restrict__ ZlT, float* __restrict__ Zn) {
  const int idx = blockIdx.x;
  const int mat = idx >> 6;
  const int cg = (idx >> 3) & 7, kt = idx & 7;
  const int c0 = cg * 64;
  const float* Z = (mat == 0) ? zq : (mat == 1) ? zk : zv;
  __shared__ float tile[64][68];
  const int t = threadIdx.x;
  {
    int kl = t >> 2;
    const float* src = Z + (size_t)(kt * 64 + kl) * 512 + c0 + (t & 3) * 16;
    #pragma unroll
    for (int j = 0; j < 4; ++j) {
      float4 v = *(const float4*)(src + 4 * j);
      *(float4*)&tile[kl][(t & 3) * 16 + 4 * j] = v;
    }
  }
  __syncthreads();
  const int cl = t >> 2, kg4 = t & 3;
  const size_t zo = (size_t)mat * 512 * 512;
  float csum = 0.f;
  #pragma unroll
  for (int jj = 0; jj < 4; ++jj) {
    u16 hb[4], lb[4];
    #pragma unroll
    for (int qq = 0; qq < 4; ++qq) {
      float zval = tile[kg4 * 16 + jj * 4 + qq][cl];
      csum = fmaf(zval, zval, csum);
      u16 hh = f2bf(zval);
      hb[qq] = hh;
      lb[qq] = f2bf(zval - bf2f(hh));
    }
    size_t o = zo + (size_t)(c0 + cl) * 512 + kt * 64 + kg4 * 16 + jj * 4;
    *(ushort4*)(ZhT + o) = make_ushort4(hb[0], hb[1], hb[2], hb[3]);
    *(ushort4*)(ZlT + o) = make_ushort4(lb[0], lb[1], lb[2], lb[3]);
  }
  csum += __shfl_xor(csum, 1);
  csum += __shfl_xor(csum, 2);
  if (kg4 == 0) atomicAdd(&Zn[mat * 512 + c0 + cl], csum);
}

// ---------------- proj_gemm: bf16x2-split MFMA GEMM + h_linear epilogue --------------
__global__ __launch_bounds__(256) void proj_gemm(
    const u16* __restrict__ Xh, const u16* __restrict__ Xl,
    const u16* __restrict__ ZhT, const u16* __restrict__ ZlT,
    const float* __restrict__ Xn, const float* __restrict__ Zn,
    const float* __restrict__ rq, const float* __restrict__ rk, const float* __restrict__ rv,
    float* __restrict__ Vtmp, float* __restrict__ Vn) {
  const int m0 = blockIdx.x * 64;
  const int n0 = blockIdx.y * 128;
  const int mat = blockIdx.z;
  const size_t xoff = (size_t)mat * 4096 * 512;
  const size_t zoff = (size_t)mat * 512 * 512;
  const int t = threadIdx.x, wv = t >> 6, lane = t & 63;
  const int l15 = lane & 15, quad = lane >> 4;
  const int wm = wv >> 1, wn = wv & 1;

  __shared__ __align__(16) u16 SM[12288];
  __shared__ float lams[64], lam1s[64], wmxs[128], wmys[128], wmzs[128];

  if (t < 64) {
    float x2 = Xn[mat * 4096 + m0 + t];
    float lam = 2.f / fmaxf(1.f - x2, EPSf);
    lams[t] = lam; lam1s[t] = lam - 1.f;
  }
  if (t < 128) {
    float zn = fmaxf(sqrtf(Zn[mat * 512 + n0 + t]), EPSf);
    const float* R = (mat == 0) ? rq : (mat == 1) ? rk : rv;
    float tr = 2.f * R[n0 + t];
    float e = expf(tr), ei = 1.f / e;
    wmxs[t] = 0.5f * (e + ei) / zn;
    wmys[t] = 0.5f * (e - ei);
    wmzs[t] = 2.f * zn;
  }

  f32x4 acc[2][4];
  #pragma unroll
  for (int i = 0; i < 2; ++i)
    #pragma unroll
    for (int j = 0; j < 4; ++j) acc[i][j] = (f32x4){0.f, 0.f, 0.f, 0.f};

  const u16* gs[6];
  u16* ld[6];
  #pragma unroll
  for (int ci = 0; ci < 6; ++ci) {
    int c = wv + 4 * ci;
    const u16* arr; int row0, lo;
    if (c < 4)       { arr = Xh + xoff;  row0 = m0 + 16 * c;        lo = c * 512; }
    else if (c < 8)  { arr = Xl + xoff;  row0 = m0 + 16 * (c - 4);  lo = 2048 + (c - 4) * 512; }
    else if (c < 16) { arr = ZhT + zoff; row0 = n0 + 16 * (c - 8);  lo = 4096 + (c - 8) * 512; }
    else             { arr = ZlT + zoff; row0 = n0 + 16 * (c - 16); lo = 8192 + (c - 16) * 512; }
    gs[ci] = arr + (size_t)(row0 + (lane >> 2)) * 512 + (lane & 3) * 8;
    ld[ci] = SM + lo;
  }

  for (int k0 = 0; k0 < 512; k0 += 32) {
    __syncthreads();
    #pragma unroll
    for (int ci = 0; ci < 6; ++ci) gll16(gs[ci] + k0, ld[ci]);
    __syncthreads();
    bf16x8 ah[2], al[2], bh_[4], bl_[4];
    #pragma unroll
    for (int i = 0; i < 2; ++i) {
      int ra = wm * 32 + i * 16 + l15;
      ah[i] = *(const bf16x8*)&SM[ra * 32 + quad * 8];
      al[i] = *(const bf16x8*)&SM[2048 + ra * 32 + quad * 8];
    }
    #pragma unroll
    for (int j = 0; j < 4; ++j) {
      int rb = wn * 64 + j * 16 + l15;
      bh_[j] = *(const bf16x8*)&SM[4096 + rb * 32 + quad * 8];
      bl_[j] = *(const bf16x8*)&SM[8192 + rb * 32 + quad * 8];
    }
    #pragma unroll
    for (int i = 0; i < 2; ++i)
      #pragma unroll
      for (int j = 0; j < 4; ++j) {
        acc[i][j] = __builtin_amdgcn_mfma_f32_16x16x32_bf16(ah[i], bh_[j], acc[i][j], 0, 0, 0);
        acc[i][j] = __builtin_amdgcn_mfma_f32_16x16x32_bf16(ah[i], bl_[j], acc[i][j], 0, 0, 0);
        acc[i][j] = __builtin_amdgcn_mfma_f32_16x16x32_bf16(al[i], bh_[j], acc[i][j], 0, 0, 0);
      }
  }

  #pragma unroll
  for (int i = 0; i < 2; ++i) {
    float rsum[4] = {0.f, 0.f, 0.f, 0.f};
    #pragma unroll
    for (int j = 0; j < 4; ++j) {
      int nl = wn * 64 + j * 16 + l15;
      float wx = wmxs[nl], wy = wmys[nl], wz = wmzs[nl];
      #pragma unroll
      for (int r = 0; r < 4; ++r) {
        int ml = wm * 32 + i * 16 + quad * 4 + r;
        float tt = lams[ml] * acc[i][j][r] * wx - lam1s[ml] * wy;
        float v = wz * logf(tt + sqrtf(fmaf(tt, tt, 1.f)));
        Vtmp[xoff + (size_t)(m0 + ml) * 512 + (n0 + nl)] = v;
        rsum[r] = fmaf(v, v, rsum[r]);
      }
    }
    #pragma unroll
    for (int r = 0; r < 4; ++r) {
      rsum[r] += __shfl_xor(rsum[r], 1);
      rsum[r] += __shfl_xor(rsum[r], 2);
      rsum[r] += __shfl_xor(rsum[r], 4);
      rsum[r] += __shfl_xor(rsum[r], 8);
    }
    if (l15 == 0) {
      #pragma unroll
      for (int r = 0; r < 4; ++r)
        atomicAdd(&Vn[mat * 4096 + m0 + wm * 32 + i * 16 + quad * 4 + r], rsum[r]);
    }
  }
}

// ---------------- pack (merged): qk relayout+scalars, v transpose+lam-fold ----------
__global__ __launch_bounds__(256) void pack(
    const float* __restrict__ Vtmp, const float* __restrict__ Vn,
    u16* __restrict__ Qh, u16* __restrict__ Kh, u16* __restrict__ VTb,
    float* __restrict__ q2a, float* __restrict__ aqa, float4* __restrict__ ksc) {
  __shared__ u16 tile[64][72];
  __shared__ float lams[64];
  const int t = threadIdx.x;
  if (blockIdx.x < 256) {
    const int mat = blockIdx.x >> 7;       // 0=Q, 1=K
    const int rb = blockIdx.x & 127;
    const int r = t >> 3, h = t & 7;
    const int row = rb * 32 + r;
    const size_t gr = (size_t)mat * 4096 + row;
    const float sc = 1.f / (1.f + sqrtf(1.f + Vn[gr]));
    const float* src = Vtmp + gr * 512 + h * 64;
    const int b = row >> 10, s = row & 1023;
    u16* dst = (mat ? Kh : Qh) + ((size_t)(b * 8 + h) * 1024 + s) * 64;
    float nrm = 0.f;
    #pragma unroll
    for (int j = 0; j < 16; ++j) {
      float4 x = *(const float4*)(src + 4 * j);
      u16 u0 = f2bf(x.x * sc), u1 = f2bf(x.y * sc), u2 = f2bf(x.z * sc), u3 = f2bf(x.w * sc);
      *(ushort4*)(dst + 4 * j) = make_ushort4(u0, u1, u2, u3);
      float f0 = bf2f(u0), f1 = bf2f(u1), f2 = bf2f(u2), f3 = bf2f(u3);
      nrm += f0 * f0 + f1 * f1 + f2 * f2 + f3 * f3;
    }
    const size_t so = (size_t)(b * 8 + h) * 1024 + s;
    if (mat == 0) { q2a[so] = nrm; aqa[so] = 1.f / fmaxf(1.f - nrm, EPSf); }
    else {
      float2 kk = make_float2(nrm, 2.f / fmaxf(1.f - nrm, EPSf));
      *(float2*)&ksc[so] = kk;              // .x = k2, .y = ck
    }
  } else {
    const int idx = blockIdx.x - 256;
    const int bh = idx >> 4, st = idx & 15;
    const int b = bh >> 3, h = bh & 7;
    {
      const int s = t >> 2, dg = t & 3;
      const size_t gr = (size_t)2 * 4096 + b * 1024 + st * 64 + s;
      const float sc = 1.f / (1.f + sqrtf(1.f + Vn[gr]));
      const float* src = Vtmp + gr * 512 + h * 64 + dg * 16;
      float nrm = 0.f;
      #pragma unroll
      for (int j = 0; j < 4; ++j) {
        float4 x = *(const float4*)(src + 4 * j);
        u16 u0 = f2bf(x.x * sc), u1 = f2bf(x.y * sc), u2 = f2bf(x.z * sc), u3 = f2bf(x.w * sc);
        *(ushort4*)&tile[s][dg * 16 + 4 * j] = make_ushort4(u0, u1, u2, u3);
        float f0 = bf2f(u0), f1 = bf2f(u1), f2 = bf2f(u2), f3 = bf2f(u3);
        nrm += f0 * f0 + f1 * f1 + f2 * f2 + f3 * f3;
      }
      nrm += __shfl_xor(nrm, 1);
      nrm += __shfl_xor(nrm, 2);
      if (dg == 0) {
        float lam = 2.f / fmaxf(1.f - nrm, EPSf);
        lams[s] = lam;
        ((float*)&ksc[(size_t)bh * 1024 + st * 64 + s])[3] = lam - 1.f;  // .w = lam_v - 1
      }
    }
    __syncthreads();
    const int d = t >> 2, sg = t & 3;
    u16 ob[16];
    #pragma unroll
    for (int j = 0; j < 16; ++j) {
      int ss = sg * 16 + j;
      ob[j] = f2bf(bf2f(tile[ss][d]) * lams[ss]);
    }
    u16* dst = VTb + ((size_t)bh * 64 + d) * 1024 + st * 64 + sg * 16;
    #pragma unroll
    for (int j = 0; j < 4; ++j)
      *(ushort4*)(dst + 4 * j) = make_ushort4(ob[4 * j], ob[4 * j + 1], ob[4 * j + 2], ob[4 * j + 3]);
  }
}

// ---------------- attn: software-pipelined (phase B one kt behind phase A) -----------
// grid (32 bh, 16 q-tiles of 64), block 256, waves = 2q x 2kt.
__global__ __launch_bounds__(256, 2) void attn(
    const u16* __restrict__ Qh, const u16* __restrict__ Kh, const u16* __restrict__ VTb,
    const float* __restrict__ q2a, const float* __restrict__ aqa,
    const float4* __restrict__ ksc, float* __restrict__ out) {
  const int bh = blockIdx.x;
  const int b = bh >> 3, h = bh & 7;
  const int q0 = blockIdx.y * 64;
  const int t = threadIdx.x, wv = t >> 6, lane = t & 63;
  const int l15 = lane & 15, quad = lane >> 4;
  const int qh = wv & 1, kh = wv >> 1;   // q-half, kt-parity

  __shared__ __align__(16) u16 Ws[4][32 * 72];          // per-wave W[q][k] (single buffer;
                                                        // wave DS in-order: read-old-then-write)
  __shared__ float k2s[4][64], cks[4][64], l1s[4][64];  // per-wave k scalars
  __shared__ __align__(16) float nums[2][32][68];       // kh=1 partials for combine
  __shared__ float dens[2][32];

  const size_t qkoff = (size_t)bh * 65536;

  // Q fragments (B-operand) + per-q scalars, loop-invariant
  bf16x8 qf[2][2];
  float q2r[2], aqr[2];
  #pragma unroll
  for (int qs = 0; qs < 2; ++qs) {
    int qrow = q0 + qh * 32 + qs * 16 + l15;
    const u16* qp = Qh + qkoff + (size_t)qrow * 64 + quad * 8;
    qf[qs][0] = *(const bf16x8*)qp;
    qf[qs][1] = *(const bf16x8*)(qp + 32);
    q2r[qs] = q2a[bh * 1024 + qrow];
    aqr[qs] = aqa[bh * 1024 + qrow];
  }

  f32x4 num[2][4];
  #pragma unroll
  for (int qs = 0; qs < 2; ++qs)
    #pragma unroll
    for (int tm = 0; tm < 4; ++tm) num[qs][tm] = (f32x4){0.f, 0.f, 0.f, 0.f};
  float denp[2] = {0.f, 0.f};

  // preload K fragments + scalars for kt = kh
  bf16x8 kcur[8];
  #pragma unroll
  for (int tn = 0; tn < 4; ++tn)
    #pragma unroll
    for (int ks = 0; ks < 2; ++ks)
      kcur[tn * 2 + ks] = *(const bf16x8*)(Kh + qkoff +
          (size_t)(kh * 64 + tn * 16 + l15) * 64 + ks * 32 + quad * 8);
  float4 scur = ksc[bh * 1024 + kh * 64 + lane];

  bf16x8 vfp[8];   // V fragments of the PREVIOUS kt (phase-B input); unused at i=0
  #pragma unroll
  for (int j = 0; j < 8; ++j) vfp[j] = (bf16x8){0,0,0,0,0,0,0,0};

  #pragma unroll 2
  for (int i = 0; i < 8; ++i) {
    const int ktc = kh + 2 * i;
    const int kti = (i < 7) ? ktc + 2 : ktc;

    // (1) read previous iteration's W early (data from iter i-1; wave-private, in-order)
    bf16x8 wfp[2][2];
    #pragma unroll
    for (int qs = 0; qs < 2; ++qs)
      #pragma unroll
      for (int ks = 0; ks < 2; ++ks)
        wfp[qs][ks] = *(const bf16x8*)&Ws[wv][(qs * 16 + l15) * 72 + ks * 32 + quad * 8];

    // (2) current kt's k scalars into LDS (lane -> chain-layout redistribution)
    k2s[wv][lane] = scur.x;
    cks[wv][lane] = scur.y;
    l1s[wv][lane] = scur.w;

    // (3) phase A + weight chain for kt_i -> overwrite Ws
    #pragma unroll
    for (int tn = 0; tn < 4; ++tn) {
      const float4 k2v = *(const float4*)&k2s[wv][tn * 16 + quad * 4];
      const float4 ckv = *(const float4*)&cks[wv][tn * 16 + quad * 4];
      const float4 l1v = *(const float4*)&l1s[wv][tn * 16 + quad * 4];
      #pragma unroll
      for (int qs = 0; qs < 2; ++qs) {
        f32x4 s = (f32x4){0.f, 0.f, 0.f, 0.f};
        s = __builtin_amdgcn_mfma_f32_16x16x32_bf16(kcur[tn * 2 + 0], qf[qs][0], s, 0, 0, 0);
        s = __builtin_amdgcn_mfma_f32_16x16x32_bf16(kcur[tn * 2 + 1], qf[qs][1], s, 0, 0, 0);
        unsigned up[2];
        #pragma unroll
        for (int pr = 0; pr < 2; ++pr) {
          float w2[2];
          #pragma unroll
          for (int e = 0; e < 2; ++e) {
            const int r = pr * 2 + e;
            float d2 = fmaxf(fmaf(-2.f, s[r], q2r[qs] + ((const float*)&k2v)[r]), 0.f);
            float u = fmaxf(d2 * ((const float*)&ckv)[r] * aqr[qs], EPSf);
            w2[e] = (1.f + u) - sqrtf(fmaf(u, u, u + u));
          }
          union { __hip_bfloat162 h2; unsigned u; } cv;
          cv.h2 = __float22bfloat162_rn(make_float2(w2[0], w2[1]));
          up[pr] = cv.u;
          float wlo = __uint_as_float(cv.u << 16);
          float whi = __uint_as_float(cv.u & 0xffff0000u);
          denp[qs] = fmaf(wlo, ((const float*)&l1v)[pr * 2 + 0], denp[qs]);
          denp[qs] = fmaf(whi, ((const float*)&l1v)[pr * 2 + 1], denp[qs]);
        }
        *(uint2*)&Ws[wv][(qs * 16 + l15) * 72 + tn * 16 + quad * 4] = make_uint2(up[0], up[1]);
      }
    }

    // (4) refill kcur for kt_{i+1} (kcur dead after phase A issues) + next scalars
    #pragma unroll
    for (int tn = 0; tn < 4; ++tn)
      #pragma unroll
      for (int ks = 0; ks < 2; ++ks)
        kcur[tn * 2 + ks] = *(const bf16x8*)(Kh + qkoff +
            (size_t)(kti * 64 + tn * 16 + l15) * 64 + ks * 32 + quad * 8);
    float4 snxt = ksc[bh * 1024 + kti * 64 + lane];

    // (5) phase B for kt_{i-1} (wfp from step 1, vfp loaded last iteration)
    if (i) {
      #pragma unroll
      for (int qs = 0; qs < 2; ++qs)
        #pragma unroll
        for (int ks = 0; ks < 2; ++ks)
          #pragma unroll
          for (int tm = 0; tm < 4; ++tm)
            num[qs][tm] = __builtin_amdgcn_mfma_f32_16x16x32_bf16(
                vfp[tm * 2 + ks], wfp[qs][ks], num[qs][tm], 0, 0, 0);
    }

    // (6) V fragments for kt_i (consumed next iteration / epilogue)
    #pragma unroll
    for (int tm = 0; tm < 4; ++tm)
      #pragma unroll
      for (int ks = 0; ks < 2; ++ks)
        vfp[tm * 2 + ks] = *(const bf16x8*)(VTb + qkoff +
            (size_t)(tm * 16 + l15) * 1024 + ktc * 64 + ks * 32 + quad * 8);

    scur = snxt;
  }

  // epilogue: drain phase B for the last kt (Ws holds iter-7 data)
  {
    #pragma unroll
    for (int qs = 0; qs < 2; ++qs)
      #pragma unroll
      for (int ks = 0; ks < 2; ++ks) {
        const bf16x8 wf = *(const bf16x8*)&Ws[wv][(qs * 16 + l15) * 72 + ks * 32 + quad * 8];
        #pragma unroll
        for (int tm = 0; tm < 4; ++tm)
          num[qs][tm] = __builtin_amdgcn_mfma_f32_16x16x32_bf16(
              vfp[tm * 2 + ks], wf, num[qs][tm], 0, 0, 0);
      }
  }

  // quad-reduce den partials
  #pragma unroll
  for (int qs = 0; qs < 2; ++qs) {
    denp[qs] += __shfl_xor(denp[qs], 16);
    denp[qs] += __shfl_xor(denp[qs], 32);
  }
  // 2-way kt combine through LDS
  if (kh == 1) {
    #pragma unroll
    for (int qs = 0; qs < 2; ++qs) {
      #pragma unroll
      for (int tm = 0; tm < 4; ++tm)
        *(float4*)&nums[qh][qs * 16 + l15][tm * 16 + quad * 4] =
            make_float4(num[qs][tm][0], num[qs][tm][1], num[qs][tm][2], num[qs][tm][3]);
      if (quad == 0) dens[qh][qs * 16 + l15] = denp[qs];
    }
  }
  __syncthreads();
  if (kh == 0) {
    #pragma unroll
    for (int qs = 0; qs < 2; ++qs) {
      float den = denp[qs] + dens[qh][qs * 16 + l15];
      den = (fabsf(den) < EPSf) ? EPSf : den;
      float inv = 1.f / den;
      float mv[4][4];
      float p = 0.f;
      #pragma unroll
      for (int tm = 0; tm < 4; ++tm) {
        float4 o = *(const float4*)&nums[qh][qs * 16 + l15][tm * 16 + quad * 4];
        mv[tm][0] = (num[qs][tm][0] + o.x) * inv;
        mv[tm][1] = (num[qs][tm][1] + o.y) * inv;
        mv[tm][2] = (num[qs][tm][2] + o.z) * inv;
        mv[tm][3] = (num[qs][tm][3] + o.w) * inv;
        p = fmaf(mv[tm][0], mv[tm][0], p); p = fmaf(mv[tm][1], mv[tm][1], p);
        p = fmaf(mv[tm][2], mv[tm][2], p); p = fmaf(mv[tm][3], mv[tm][3], p);
      }
      p += __shfl_xor(p, 16);
      p += __shfl_xor(p, 32);
      float mn = sqrtf(p);
      float mnc = fmaxf(mn, EPSf);
      float tt2 = fminf(mnc, 1.f - 1e-6f);
      float scale = tt2 / ((1.f + sqrtf(fmaxf(1.f - tt2 * tt2, 0.f))) * mnc);
      const size_t qg = (size_t)b * 1024 + q0 + qh * 32 + qs * 16 + l15;
      #pragma unroll
      for (int tm = 0; tm < 4; ++tm) {
        float4 o = make_float4(mv[tm][0] * scale, mv[tm][1] * scale,
                               mv[tm][2] * scale, mv[tm][3] * scale);
        *(float4*)(out + qg * 512 + h * 64 + tm * 16 + quad * 4) = o;
      }
    }
  }
}

// ---------------- host ----------------
extern "C" void kernel_launch(void* const* d_in, const int* in_sizes, int n_in,
                              void* d_out, int out_size, void* d_ws, size_t ws_size,
                              hipStream_t stream) {
  (void)in_sizes; (void)n_in; (void)out_size; (void)ws_size;
  const float* q  = (const float*)d_in[0];
  const float* k  = (const float*)d_in[1];
  const float* v  = (const float*)d_in[2];
  const float* zq = (const float*)d_in[3];
  const float* rq = (const float*)d_in[4];
  const float* zk = (const float*)d_in[5];
  const float* rk = (const float*)d_in[6];
  const float* zv = (const float*)d_in[7];
  const float* rv = (const float*)d_in[8];

  unsigned char* ws = (unsigned char*)d_ws;
  // phase-1 region:
  u16*   Xh   = (u16*)(ws + 0);          // 12582912
  u16*   Xl   = (u16*)(ws + 12582912);   // 12582912
  u16*   ZhT  = (u16*)(ws + 25165824);   // 1572864
  u16*   ZlT  = (u16*)(ws + 26738688);   // 1572864
  float* Vtmp = (float*)(ws + 28311552); // 25165824
  float* Xn   = (float*)(ws + 53477376); // 49152
  float* Vn   = (float*)(ws + 53526528); // 49152
  float* Zn   = (float*)(ws + 53575680); // 6144
  // phase-2 packed arrays overlay the dead Xh/Xl region (proj_gemm done):
  u16*   Qh   = (u16*)(ws + 0);          // 4194304
  u16*   Kh   = (u16*)(ws + 4194304);    // 4194304
  u16*   VTb  = (u16*)(ws + 8388608);    // 4194304
  float* q2a  = (float*)(ws + 12582912); // 131072
  float* aqa  = (float*)(ws + 12713984); // 131072
  float4* ksc = (float4*)(ws + 12845056);// 524288

  split_x<<<6144, 256, 0, stream>>>(q, k, v, Xh, Xl, Xn, Vn, Zn);
  split_z<<<192, 256, 0, stream>>>(zq, zk, zv, ZhT, ZlT, Zn);
  proj_gemm<<<dim3(64, 4, 3), 256, 0, stream>>>(Xh, Xl, ZhT, ZlT, Xn, Zn, rq, rk, rv, Vtmp, Vn);
  pack<<<768, 256, 0, stream>>>(Vtmp, Vn, Qh, Kh, VTb, q2a, aqa, ksc);
  attn<<<dim3(32, 16), 256, 0, stream>>>(Qh, Kh, VTb, q2a, aqa, ksc, (float*)d_out);
}